// Round 1
// baseline (842.968 us; speedup 1.0000x reference)
//
#include <hip/hip_runtime.h>
#include <math.h>

#define NB 4096
#define DD 1024
#define CC 256
#define NE 8

// ws layout (bytes):
//   0: counts[8] int | 32: fill[8] int | 64: off[9] int | 104: toff[9] int
// 144: imp[8] f32    | 176: load[8] f32
// 256: gval f32[8192] | 33024: eidx int[8192] | 65792: rowlist int[8192]

__global__ __launch_bounds__(256) void gating_kernel(
    const float* __restrict__ sf, const float* __restrict__ noise,
    const float* __restrict__ wg, const float* __restrict__ wn,
    int* __restrict__ counts, float* __restrict__ gval, int* __restrict__ eidx,
    float* __restrict__ impv, float* __restrict__ loadv)
{
    int t = threadIdx.x;
    int lane = t & 63;
    int w = t >> 6;
    int b = blockIdx.x * 4 + w;
    const float* x = sf + (size_t)b * DD;

    float accg[8], accn[8];
#pragma unroll
    for (int e = 0; e < 8; e++) { accg[e] = 0.f; accn[e] = 0.f; }

#pragma unroll
    for (int q = 0; q < 4; q++) {
        float4 xv = *(const float4*)(x + lane * 4 + q * 256);
#pragma unroll
        for (int j = 0; j < 4; j++) {
            float xs = (j == 0) ? xv.x : (j == 1) ? xv.y : (j == 2) ? xv.z : xv.w;
            int d = lane * 4 + q * 256 + j;
            float4 g0 = *(const float4*)(wg + (size_t)d * 8);
            float4 g1 = *(const float4*)(wg + (size_t)d * 8 + 4);
            float4 n0 = *(const float4*)(wn + (size_t)d * 8);
            float4 n1 = *(const float4*)(wn + (size_t)d * 8 + 4);
            accg[0] += xs * g0.x; accg[1] += xs * g0.y; accg[2] += xs * g0.z; accg[3] += xs * g0.w;
            accg[4] += xs * g1.x; accg[5] += xs * g1.y; accg[6] += xs * g1.z; accg[7] += xs * g1.w;
            accn[0] += xs * n0.x; accn[1] += xs * n0.y; accn[2] += xs * n0.z; accn[3] += xs * n0.w;
            accn[4] += xs * n1.x; accn[5] += xs * n1.y; accn[6] += xs * n1.z; accn[7] += xs * n1.w;
        }
    }
#pragma unroll
    for (int e = 0; e < 8; e++) {
        for (int s = 1; s < 64; s <<= 1) {
            accg[e] += __shfl_xor(accg[e], s);
            accn[e] += __shfl_xor(accn[e], s);
        }
    }

    if (lane == 0) {
        float clean[8], stdv[8], noisy[8], p[8];
        float mx = -1e30f;
#pragma unroll
        for (int e = 0; e < 8; e++) {
            clean[e] = accg[e];
            float xn = accn[e];
            float sp = (xn > 0.f) ? (xn + log1pf(expf(-xn))) : log1pf(expf(xn));
            stdv[e] = sp + 0.01f;
            noisy[e] = clean[e] + noise[(size_t)b * 8 + e] * stdv[e];
            mx = fmaxf(mx, noisy[e]);
        }
        float se = 0.f;
#pragma unroll
        for (int e = 0; e < 8; e++) { p[e] = expf(noisy[e] - mx); se += p[e]; }
        float inv = 1.f / se;
#pragma unroll
        for (int e = 0; e < 8; e++) p[e] *= inv;

        int i0 = -1, i1 = -1, i2 = -1;
        float p0 = -1e30f, p1v = -1e30f, p2v = -1e30f;
#pragma unroll
        for (int e = 0; e < 8; e++) if (p[e] > p0) { p0 = p[e]; i0 = e; }
#pragma unroll
        for (int e = 0; e < 8; e++) if (e != i0 && p[e] > p1v) { p1v = p[e]; i1 = e; }
#pragma unroll
        for (int e = 0; e < 8; e++) if (e != i0 && e != i1 && p[e] > p2v) { p2v = p[e]; i2 = e; }
        (void)i2;

        float den = p0 + p1v + 1e-6f;
        float g0 = p0 / den, g1 = p1v / den;
        eidx[2 * b] = i0; eidx[2 * b + 1] = i1;
        gval[2 * b] = g0; gval[2 * b + 1] = g1;
        atomicAdd(counts + i0, 1);
        atomicAdd(counts + i1, 1);
        atomicAdd(impv + i0, g0);
        atomicAdd(impv + i1, g1);

        const float is2 = 0.70710678118654752440f;
#pragma unroll
        for (int e = 0; e < 8; e++) {
            float pin  = 0.5f * (1.f + erff((clean[e] - p2v) / stdv[e] * is2));
            float pout = 0.5f * (1.f + erff((clean[e] - p1v) / stdv[e] * is2));
            float v = (noisy[e] > p2v) ? pin : pout;
            atomicAdd(loadv + e, v);
        }
    }
}

__global__ void scan_loss_kernel(const int* __restrict__ counts, int* __restrict__ off,
                                 int* __restrict__ toff, const float* __restrict__ impv,
                                 const float* __restrict__ loadv, float* __restrict__ out_loss)
{
    if (threadIdx.x == 0) {
        int o = 0, to = 0;
        off[0] = 0; toff[0] = 0;
        for (int e = 0; e < 8; e++) {
            o += counts[e]; off[e + 1] = o;
            to += (counts[e] + 31) / 32; toff[e + 1] = to;
        }
        float mi = 0.f, ml = 0.f;
        for (int e = 0; e < 8; e++) { mi += impv[e]; ml += loadv[e]; }
        mi *= 0.125f; ml *= 0.125f;
        float vi = 0.f, vl = 0.f;
        for (int e = 0; e < 8; e++) {
            float di = impv[e] - mi; vi += di * di;
            float dl = loadv[e] - ml; vl += dl * dl;
        }
        vi /= 7.f; vl /= 7.f;
        float cvi = vi / (mi * mi + 1e-10f);
        float cvl = vl / (ml * ml + 1e-10f);
        out_loss[0] = (cvi + cvl) * 0.01f;
    }
}

__global__ void fill_kernel(const int* __restrict__ eidx, int* __restrict__ fill,
                            const int* __restrict__ off, int* __restrict__ rowlist)
{
    int p = blockIdx.x * 256 + threadIdx.x;
    if (p < 2 * NB) {
        int e = eidx[p];
        int pos = atomicAdd(fill + e, 1);
        rowlist[off[e] + pos] = p;
    }
}

__global__ __launch_bounds__(256) void combine_kernel(
    const float* __restrict__ sf, const float* __restrict__ of,
    const float* __restrict__ ppf, const float* __restrict__ pvf,
    const float* __restrict__ Ws, const float* __restrict__ Wo, const float* __restrict__ Wp,
    const int* __restrict__ counts, const int* __restrict__ off, const int* __restrict__ toff,
    const int* __restrict__ rowlist, const float* __restrict__ gval,
    float* __restrict__ out)
{
    int bid = blockIdx.x;
    int strm = blockIdx.z;
    if (bid >= toff[8]) return;
    int e = 0;
    while (bid >= toff[e + 1]) e++;
    int tm = bid - toff[e];
    int cnt = counts[e];
    int obase = off[e];

    __shared__ float As[32][36];
    __shared__ float Bs[32][256];
    __shared__ int rows_s[32];
    __shared__ float gate_s[32];

    int t = threadIdx.x;
    if (t < 32) {
        int m = tm * 32 + t;
        if (m < cnt) {
            int pid = rowlist[obase + m];
            rows_s[t] = pid >> 1;
            gate_s[t] = gval[pid];
        } else {
            rows_s[t] = -1;
            gate_s[t] = 0.f;
        }
    }
    __syncthreads();

    const float* W = ((strm == 0) ? Ws : (strm == 1) ? Wo : Wp) + (size_t)e * DD * CC;
    float acc[2][16];
#pragma unroll
    for (int i = 0; i < 2; i++)
#pragma unroll
        for (int j = 0; j < 16; j++) acc[i][j] = 0.f;

    int tx = t & 15, ty = t >> 4;
    int r_st = t >> 3, d4 = t & 7;
    int row_st = rows_s[r_st];

    for (int k0 = 0; k0 < DD; k0 += 32) {
        // stage A (transposed: As[k][row])
        float4 v = make_float4(0.f, 0.f, 0.f, 0.f);
        if (row_st >= 0) {
            int d = k0 + d4 * 4;
            if (strm == 0)      v = *(const float4*)(sf + (size_t)row_st * DD + d);
            else if (strm == 1) v = *(const float4*)(of + (size_t)row_st * DD + d);
            else v = (d < 512) ? *(const float4*)(ppf + (size_t)row_st * 512 + d)
                               : *(const float4*)(pvf + (size_t)row_st * 512 + (d - 512));
        }
        As[d4 * 4 + 0][r_st] = v.x;
        As[d4 * 4 + 1][r_st] = v.y;
        As[d4 * 4 + 2][r_st] = v.z;
        As[d4 * 4 + 3][r_st] = v.w;
        // stage B
#pragma unroll
        for (int j = 0; j < 8; j++) {
            int vv = t + 256 * j;
            int k = vv >> 6, c4 = vv & 63;
            *(float4*)&Bs[k][c4 * 4] = *(const float4*)&W[(size_t)(k0 + k) * CC + c4 * 4];
        }
        __syncthreads();

#pragma unroll
        for (int k = 0; k < 32; k++) {
            float2 a = *(float2*)&As[k][ty * 2];
#pragma unroll
            for (int jj = 0; jj < 4; jj++) {
                float4 bb = *(float4*)&Bs[k][jj * 64 + tx * 4];
                acc[0][jj * 4 + 0] += a.x * bb.x;
                acc[0][jj * 4 + 1] += a.x * bb.y;
                acc[0][jj * 4 + 2] += a.x * bb.z;
                acc[0][jj * 4 + 3] += a.x * bb.w;
                acc[1][jj * 4 + 0] += a.y * bb.x;
                acc[1][jj * 4 + 1] += a.y * bb.y;
                acc[1][jj * 4 + 2] += a.y * bb.z;
                acc[1][jj * 4 + 3] += a.y * bb.w;
            }
        }
        __syncthreads();
    }

    // epilogue: per (row, expert) softmax over 256 cols, scale by gate, atomic add
    float* comb = out + (size_t)strm * (NB * CC);
#pragma unroll
    for (int i = 0; i < 2; i++) {
        int r = ty * 2 + i;
        int row = rows_s[r];
        if (row < 0) continue;
        float mx = -1e30f;
#pragma unroll
        for (int j = 0; j < 16; j++) mx = fmaxf(mx, acc[i][j]);
        for (int s = 1; s < 16; s <<= 1) mx = fmaxf(mx, __shfl_xor(mx, s, 16));
        float se = 0.f;
#pragma unroll
        for (int j = 0; j < 16; j++) { acc[i][j] = expf(acc[i][j] - mx); se += acc[i][j]; }
        for (int s = 1; s < 16; s <<= 1) se += __shfl_xor(se, s, 16);
        float scale = gate_s[r] / se;
#pragma unroll
        for (int jj = 0; jj < 4; jj++)
#pragma unroll
            for (int jo = 0; jo < 4; jo++) {
                int col = jj * 64 + tx * 4 + jo;
                atomicAdd(comb + (size_t)row * CC + col, acc[i][jj * 4 + jo] * scale);
            }
    }
}

__global__ void log_kernel(float* __restrict__ out, int n4)
{
    int i = blockIdx.x * 256 + threadIdx.x;
    if (i >= n4) return;
    float4 v = *(float4*)(out + (size_t)i * 4);
    const float EPSL = 2.2204460492503131e-16f;
    v.x = logf(v.x == 0.f ? EPSL : v.x);
    v.y = logf(v.y == 0.f ? EPSL : v.y);
    v.z = logf(v.z == 0.f ? EPSL : v.z);
    v.w = logf(v.w == 0.f ? EPSL : v.w);
    *(float4*)(out + (size_t)i * 4) = v;
}

extern "C" void kernel_launch(void* const* d_in, const int* in_sizes, int n_in,
                              void* d_out, int out_size, void* d_ws, size_t ws_size,
                              hipStream_t stream) {
    (void)in_sizes; (void)n_in; (void)ws_size;
    const float* sf    = (const float*)d_in[0];
    const float* of    = (const float*)d_in[1];
    const float* ppf   = (const float*)d_in[2];
    const float* pvf   = (const float*)d_in[3];
    const float* noise = (const float*)d_in[4];
    const float* wg    = (const float*)d_in[5];
    const float* wn    = (const float*)d_in[6];
    const float* Ws    = (const float*)d_in[7];
    const float* Wo    = (const float*)d_in[8];
    const float* Wp    = (const float*)d_in[9];
    float* out = (float*)d_out;

    char* ws = (char*)d_ws;
    int*   counts  = (int*)(ws + 0);
    int*   fill    = (int*)(ws + 32);
    int*   off     = (int*)(ws + 64);
    int*   toff    = (int*)(ws + 104);
    float* impv    = (float*)(ws + 144);
    float* loadv   = (float*)(ws + 176);
    float* gval    = (float*)(ws + 256);
    int*   eidx    = (int*)(ws + 256 + 32768);
    int*   rowlist = (int*)(ws + 256 + 65536);

    hipMemsetAsync(ws, 0, 256, stream);
    hipMemsetAsync(d_out, 0, (size_t)out_size * sizeof(float), stream);

    gating_kernel<<<NB / 4, 256, 0, stream>>>(sf, noise, wg, wn, counts, gval, eidx, impv, loadv);
    scan_loss_kernel<<<1, 64, 0, stream>>>(counts, off, toff, impv, loadv, out + (out_size - 1));
    fill_kernel<<<(2 * NB) / 256, 256, 0, stream>>>(eidx, fill, off, rowlist);
    combine_kernel<<<dim3(2 * NB / 32 + 8, 1, 3), 256, 0, stream>>>(
        sf, of, ppf, pvf, Ws, Wo, Wp, counts, off, toff, rowlist, gval, out);
    int n4 = (out_size - 1) / 4;
    log_kernel<<<(n4 + 255) / 256, 256, 0, stream>>>(out, n4);
}

// Round 2
// 477.499 us; speedup vs baseline: 1.7654x; 1.7654x over previous
//
#include <hip/hip_runtime.h>
#include <math.h>

#define NB 4096
#define DD 1024
#define CC 256
#define NE 8
#define NGBLK 1024   // gating blocks (4 rows each)

// ws layout (bytes):
//   0:   fill[8] int
//   64:  off[9] int | 104: toff[9] int | 144: counts[8] int
//   256:    gval   f32[8192]
//   33024:  eidx   int[8192]
//   65792:  rowlist int[8192]
//   98560:  cnt_p  f32[NGBLK*8]
//   131328: imp_p  f32[NGBLK*8]
//   164096: load_p f32[NGBLK*8]

__global__ __launch_bounds__(256) void gating_kernel(
    const float* __restrict__ sf, const float* __restrict__ noise,
    const float* __restrict__ wg, const float* __restrict__ wn,
    float* __restrict__ gval, int* __restrict__ eidx,
    float* __restrict__ cnt_p, float* __restrict__ imp_p, float* __restrict__ load_p)
{
    int t = threadIdx.x;
    int lane = t & 63;
    int w = t >> 6;
    int b = blockIdx.x * 4 + w;
    const float* x = sf + (size_t)b * DD;

    float accg[8], accn[8];
#pragma unroll
    for (int e = 0; e < 8; e++) { accg[e] = 0.f; accn[e] = 0.f; }

#pragma unroll
    for (int q = 0; q < 16; q++) {
        int d = q * 64 + lane;          // lane-consecutive d: coalesced
        float xs = x[d];
        float4 g0 = *(const float4*)(wg + (size_t)d * 8);
        float4 g1 = *(const float4*)(wg + (size_t)d * 8 + 4);
        float4 n0 = *(const float4*)(wn + (size_t)d * 8);
        float4 n1 = *(const float4*)(wn + (size_t)d * 8 + 4);
        accg[0] += xs * g0.x; accg[1] += xs * g0.y; accg[2] += xs * g0.z; accg[3] += xs * g0.w;
        accg[4] += xs * g1.x; accg[5] += xs * g1.y; accg[6] += xs * g1.z; accg[7] += xs * g1.w;
        accn[0] += xs * n0.x; accn[1] += xs * n0.y; accn[2] += xs * n0.z; accn[3] += xs * n0.w;
        accn[4] += xs * n1.x; accn[5] += xs * n1.y; accn[6] += xs * n1.z; accn[7] += xs * n1.w;
    }
#pragma unroll
    for (int e = 0; e < 8; e++) {
        for (int s = 1; s < 64; s <<= 1) {
            accg[e] += __shfl_xor(accg[e], s);
            accn[e] += __shfl_xor(accn[e], s);
        }
    }

    __shared__ float s_load[4][8], s_imp[4][8], s_cnt[4][8];

    if (lane == 0) {
        float clean[8], stdv[8], noisy[8], p[8];
        float mx = -1e30f;
#pragma unroll
        for (int e = 0; e < 8; e++) {
            clean[e] = accg[e];
            float xn = accn[e];
            float sp = (xn > 0.f) ? (xn + log1pf(expf(-xn))) : log1pf(expf(xn));
            stdv[e] = sp + 0.01f;
            noisy[e] = clean[e] + noise[(size_t)b * 8 + e] * stdv[e];
            mx = fmaxf(mx, noisy[e]);
        }
        float se = 0.f;
#pragma unroll
        for (int e = 0; e < 8; e++) { p[e] = expf(noisy[e] - mx); se += p[e]; }
        float inv = 1.f / se;
#pragma unroll
        for (int e = 0; e < 8; e++) p[e] *= inv;

        int i0 = -1, i1 = -1;
        float p0 = -1e30f, p1v = -1e30f, p2v = -1e30f;
#pragma unroll
        for (int e = 0; e < 8; e++) if (p[e] > p0) { p0 = p[e]; i0 = e; }
#pragma unroll
        for (int e = 0; e < 8; e++) if (e != i0 && p[e] > p1v) { p1v = p[e]; i1 = e; }
#pragma unroll
        for (int e = 0; e < 8; e++) if (e != i0 && e != i1 && p[e] > p2v) { p2v = p[e]; }

        float den = p0 + p1v + 1e-6f;
        float g0 = p0 / den, g1 = p1v / den;
        eidx[2 * b] = i0; eidx[2 * b + 1] = i1;
        gval[2 * b] = g0; gval[2 * b + 1] = g1;

        const float is2 = 0.70710678118654752440f;
#pragma unroll
        for (int e = 0; e < 8; e++) {
            float pin  = 0.5f * (1.f + erff((clean[e] - p2v) / stdv[e] * is2));
            float pout = 0.5f * (1.f + erff((clean[e] - p1v) / stdv[e] * is2));
            s_load[w][e] = (noisy[e] > p2v) ? pin : pout;
            s_imp[w][e]  = (e == i0) ? g0 : (e == i1) ? g1 : 0.f;
            s_cnt[w][e]  = (e == i0 || e == i1) ? 1.f : 0.f;
        }
    }
    __syncthreads();
    if (t < 8) {
        float sl = 0.f, si = 0.f, sc = 0.f;
#pragma unroll
        for (int ww = 0; ww < 4; ww++) {
            sl += s_load[ww][t]; si += s_imp[ww][t]; sc += s_cnt[ww][t];
        }
        load_p[blockIdx.x * 8 + t] = sl;
        imp_p [blockIdx.x * 8 + t] = si;
        cnt_p [blockIdx.x * 8 + t] = sc;
    }
}

__global__ void scan_loss_kernel(const float* __restrict__ cnt_p, const float* __restrict__ imp_p,
                                 const float* __restrict__ load_p,
                                 int* __restrict__ counts, int* __restrict__ off,
                                 int* __restrict__ toff, float* __restrict__ out_loss)
{
    __shared__ float s_c[64], s_i[64], s_l[64];
    __shared__ float f_c[8], f_i[8], f_l[8];
    int t = threadIdx.x;            // 64 threads
    int e = t & 7, g = t >> 3;      // 8 groups x 128 blocks
    float sc = 0.f, si = 0.f, sl = 0.f;
    for (int blk = g * 128; blk < (g + 1) * 128; blk++) {
        sc += cnt_p[blk * 8 + e];
        si += imp_p[blk * 8 + e];
        sl += load_p[blk * 8 + e];
    }
    s_c[t] = sc; s_i[t] = si; s_l[t] = sl;
    __syncthreads();
    if (t < 8) {
        float c = 0.f, i = 0.f, l = 0.f;
        for (int gg = 0; gg < 8; gg++) { c += s_c[gg * 8 + t]; i += s_i[gg * 8 + t]; l += s_l[gg * 8 + t]; }
        f_c[t] = c; f_i[t] = i; f_l[t] = l;
        counts[t] = (int)(c + 0.5f);
    }
    __syncthreads();
    if (t == 0) {
        int o = 0, to = 0;
        off[0] = 0; toff[0] = 0;
        for (int ee = 0; ee < 8; ee++) {
            int c = (int)(f_c[ee] + 0.5f);
            o += c; off[ee + 1] = o;
            to += (c + 31) / 32; toff[ee + 1] = to;
        }
        float mi = 0.f, ml = 0.f;
        for (int ee = 0; ee < 8; ee++) { mi += f_i[ee]; ml += f_l[ee]; }
        mi *= 0.125f; ml *= 0.125f;
        float vi = 0.f, vl = 0.f;
        for (int ee = 0; ee < 8; ee++) {
            float di = f_i[ee] - mi; vi += di * di;
            float dl = f_l[ee] - ml; vl += dl * dl;
        }
        vi /= 7.f; vl /= 7.f;
        out_loss[0] = (vi / (mi * mi + 1e-10f) + vl / (ml * ml + 1e-10f)) * 0.01f;
    }
}

__global__ __launch_bounds__(256) void fill_kernel(
    const int* __restrict__ eidx, int* __restrict__ fillc,
    const int* __restrict__ off, int* __restrict__ rowlist)
{
    __shared__ int lcnt[8], lbase[8];
    int t = threadIdx.x;
    if (t < 8) lcnt[t] = 0;
    __syncthreads();
    int p = blockIdx.x * 256 + t;
    int e = eidx[p];
    int lpos = atomicAdd(&lcnt[e], 1);
    __syncthreads();
    if (t < 8) lbase[t] = atomicAdd(&fillc[t], lcnt[t]);
    __syncthreads();
    rowlist[off[e] + lbase[e] + lpos] = p;
}

__global__ __launch_bounds__(256) void combine_kernel(
    const float* __restrict__ sf, const float* __restrict__ of,
    const float* __restrict__ ppf, const float* __restrict__ pvf,
    const float* __restrict__ Ws, const float* __restrict__ Wo, const float* __restrict__ Wp,
    const int* __restrict__ counts, const int* __restrict__ off, const int* __restrict__ toff,
    const int* __restrict__ rowlist, const float* __restrict__ gval,
    float* __restrict__ out)
{
    int bid = blockIdx.x;
    int strm = blockIdx.z;
    if (bid >= toff[8]) return;
    int e = 0;
    while (bid >= toff[e + 1]) e++;
    int tm = bid - toff[e];
    int cnt = counts[e];
    int obase = off[e];

    __shared__ float As[32][36];
    __shared__ float Bs[32][256];
    __shared__ int rows_s[32];
    __shared__ float gate_s[32];

    int t = threadIdx.x;
    if (t < 32) {
        int m = tm * 32 + t;
        if (m < cnt) {
            int pid = rowlist[obase + m];
            rows_s[t] = pid >> 1;
            gate_s[t] = gval[pid];
        } else {
            rows_s[t] = -1;
            gate_s[t] = 0.f;
        }
    }
    __syncthreads();

    const float* W = ((strm == 0) ? Ws : (strm == 1) ? Wo : Wp) + (size_t)e * DD * CC;
    float acc[2][16];
#pragma unroll
    for (int i = 0; i < 2; i++)
#pragma unroll
        for (int j = 0; j < 16; j++) acc[i][j] = 0.f;

    int tx = t & 15, ty = t >> 4;
    int r_st = t >> 3, d4 = t & 7;
    int row_st = rows_s[r_st];

    for (int k0 = 0; k0 < DD; k0 += 32) {
        float4 v = make_float4(0.f, 0.f, 0.f, 0.f);
        if (row_st >= 0) {
            int d = k0 + d4 * 4;
            if (strm == 0)      v = *(const float4*)(sf + (size_t)row_st * DD + d);
            else if (strm == 1) v = *(const float4*)(of + (size_t)row_st * DD + d);
            else v = (d < 512) ? *(const float4*)(ppf + (size_t)row_st * 512 + d)
                               : *(const float4*)(pvf + (size_t)row_st * 512 + (d - 512));
        }
        As[d4 * 4 + 0][r_st] = v.x;
        As[d4 * 4 + 1][r_st] = v.y;
        As[d4 * 4 + 2][r_st] = v.z;
        As[d4 * 4 + 3][r_st] = v.w;
#pragma unroll
        for (int j = 0; j < 8; j++) {
            int vv = t + 256 * j;
            int k = vv >> 6, c4 = vv & 63;
            *(float4*)&Bs[k][c4 * 4] = *(const float4*)&W[(size_t)(k0 + k) * CC + c4 * 4];
        }
        __syncthreads();

#pragma unroll
        for (int k = 0; k < 32; k++) {
            float2 a = *(float2*)&As[k][ty * 2];
#pragma unroll
            for (int jj = 0; jj < 4; jj++) {
                float4 bb = *(float4*)&Bs[k][jj * 64 + tx * 4];
                acc[0][jj * 4 + 0] += a.x * bb.x;
                acc[0][jj * 4 + 1] += a.x * bb.y;
                acc[0][jj * 4 + 2] += a.x * bb.z;
                acc[0][jj * 4 + 3] += a.x * bb.w;
                acc[1][jj * 4 + 0] += a.y * bb.x;
                acc[1][jj * 4 + 1] += a.y * bb.y;
                acc[1][jj * 4 + 2] += a.y * bb.z;
                acc[1][jj * 4 + 3] += a.y * bb.w;
            }
        }
        __syncthreads();
    }

    float* comb = out + (size_t)strm * (NB * CC);
#pragma unroll
    for (int i = 0; i < 2; i++) {
        int r = ty * 2 + i;
        int row = rows_s[r];
        if (row < 0) continue;
        float mx = -1e30f;
#pragma unroll
        for (int j = 0; j < 16; j++) mx = fmaxf(mx, acc[i][j]);
        for (int s = 1; s < 16; s <<= 1) mx = fmaxf(mx, __shfl_xor(mx, s, 16));
        float se = 0.f;
#pragma unroll
        for (int j = 0; j < 16; j++) { acc[i][j] = expf(acc[i][j] - mx); se += acc[i][j]; }
        for (int s = 1; s < 16; s <<= 1) se += __shfl_xor(se, s, 16);
        float scale = gate_s[r] / se;
#pragma unroll
        for (int jj = 0; jj < 4; jj++)
#pragma unroll
            for (int jo = 0; jo < 4; jo++) {
                int col = jj * 64 + tx * 4 + jo;
                atomicAdd(comb + (size_t)row * CC + col, acc[i][jj * 4 + jo] * scale);
            }
    }
}

__global__ void log_kernel(float* __restrict__ out, int n4)
{
    int i = blockIdx.x * 256 + threadIdx.x;
    if (i >= n4) return;
    float4 v = *(float4*)(out + (size_t)i * 4);
    const float EPSL = 2.2204460492503131e-16f;
    v.x = logf(v.x == 0.f ? EPSL : v.x);
    v.y = logf(v.y == 0.f ? EPSL : v.y);
    v.z = logf(v.z == 0.f ? EPSL : v.z);
    v.w = logf(v.w == 0.f ? EPSL : v.w);
    *(float4*)(out + (size_t)i * 4) = v;
}

extern "C" void kernel_launch(void* const* d_in, const int* in_sizes, int n_in,
                              void* d_out, int out_size, void* d_ws, size_t ws_size,
                              hipStream_t stream) {
    (void)in_sizes; (void)n_in; (void)ws_size;
    const float* sf    = (const float*)d_in[0];
    const float* of    = (const float*)d_in[1];
    const float* ppf   = (const float*)d_in[2];
    const float* pvf   = (const float*)d_in[3];
    const float* noise = (const float*)d_in[4];
    const float* wg    = (const float*)d_in[5];
    const float* wn    = (const float*)d_in[6];
    const float* Ws    = (const float*)d_in[7];
    const float* Wo    = (const float*)d_in[8];
    const float* Wp    = (const float*)d_in[9];
    float* out = (float*)d_out;

    char* ws = (char*)d_ws;
    int*   fillc   = (int*)(ws + 0);
    int*   off     = (int*)(ws + 64);
    int*   toff    = (int*)(ws + 104);
    int*   counts  = (int*)(ws + 144);
    float* gval    = (float*)(ws + 256);
    int*   eidx    = (int*)(ws + 33024);
    int*   rowlist = (int*)(ws + 65792);
    float* cnt_p   = (float*)(ws + 98560);
    float* imp_p   = (float*)(ws + 131328);
    float* load_p  = (float*)(ws + 164096);

    hipMemsetAsync(ws, 0, 256, stream);
    hipMemsetAsync(d_out, 0, (size_t)out_size * sizeof(float), stream);

    gating_kernel<<<NGBLK, 256, 0, stream>>>(sf, noise, wg, wn, gval, eidx, cnt_p, imp_p, load_p);
    scan_loss_kernel<<<1, 64, 0, stream>>>(cnt_p, imp_p, load_p, counts, off, toff, out + (out_size - 1));
    fill_kernel<<<(2 * NB) / 256, 256, 0, stream>>>(eidx, fillc, off, rowlist);
    combine_kernel<<<dim3(2 * NB / 32 + 8, 1, 3), 256, 0, stream>>>(
        sf, of, ppf, pvf, Ws, Wo, Wp, counts, off, toff, rowlist, gval, out);
    int n4 = (out_size - 1) / 4;
    log_kernel<<<(n4 + 255) / 256, 256, 0, stream>>>(out, n4);
}

// Round 4
// 349.399 us; speedup vs baseline: 2.4126x; 1.3666x over previous
//
#include <hip/hip_runtime.h>
#include <math.h>

#define NB 4096
#define DD 1024
#define CC 256
#define NE 8
#define NGBLK 1024

typedef short bf16x8 __attribute__((ext_vector_type(8)));
typedef float f32x4 __attribute__((ext_vector_type(4)));

// ws layout (bytes):
//   0:   (unused pad) | 64: off[9] | 104: toff[9] | 144: counts[8]
//   256:    gval f32[8192] | 33024: eidx int[8192] | 65792: rowlist int[8192]
//   98560:  cnt_p f32[NGBLK*8] | 131328: imp_p | 164096: load_p
//   1 MB:   Wt bf16 [24][256][1024]   (12.58 MB)  -- fast path only
//   16 MB:  Fb bf16 [3][4096][1024]   (25.17 MB)  -- fast path only
#define WT_OFF  (1u << 20)
#define FB_OFF  (16u << 20)
#define WS_FAST_NEED (41943040ull)

__device__ __forceinline__ unsigned short f2bf(float f) {
    union { float f; unsigned u; } v; v.f = f;
    unsigned x = v.u;
    return (unsigned short)((x + 0x7FFFu + ((x >> 16) & 1u)) >> 16);
}

// ---------------- gating ----------------
__global__ __launch_bounds__(256) void gating_kernel(
    const float* __restrict__ sf, const float* __restrict__ noise,
    const float* __restrict__ wg, const float* __restrict__ wn,
    float* __restrict__ gval, int* __restrict__ eidx,
    float* __restrict__ cnt_p, float* __restrict__ imp_p, float* __restrict__ load_p)
{
    int t = threadIdx.x;
    int lane = t & 63;
    int w = t >> 6;
    int b = blockIdx.x * 4 + w;
    const float* x = sf + (size_t)b * DD;

    float accg[8], accn[8];
#pragma unroll
    for (int e = 0; e < 8; e++) { accg[e] = 0.f; accn[e] = 0.f; }

#pragma unroll
    for (int q = 0; q < 16; q++) {
        int d = q * 64 + lane;
        float xs = x[d];
        float4 g0 = *(const float4*)(wg + (size_t)d * 8);
        float4 g1 = *(const float4*)(wg + (size_t)d * 8 + 4);
        float4 n0 = *(const float4*)(wn + (size_t)d * 8);
        float4 n1 = *(const float4*)(wn + (size_t)d * 8 + 4);
        accg[0] += xs * g0.x; accg[1] += xs * g0.y; accg[2] += xs * g0.z; accg[3] += xs * g0.w;
        accg[4] += xs * g1.x; accg[5] += xs * g1.y; accg[6] += xs * g1.z; accg[7] += xs * g1.w;
        accn[0] += xs * n0.x; accn[1] += xs * n0.y; accn[2] += xs * n0.z; accn[3] += xs * n0.w;
        accn[4] += xs * n1.x; accn[5] += xs * n1.y; accn[6] += xs * n1.z; accn[7] += xs * n1.w;
    }
#pragma unroll
    for (int e = 0; e < 8; e++) {
        for (int s = 1; s < 64; s <<= 1) {
            accg[e] += __shfl_xor(accg[e], s);
            accn[e] += __shfl_xor(accn[e], s);
        }
    }

    __shared__ float s_load[4][8], s_imp[4][8], s_cnt[4][8];

    if (lane == 0) {
        float clean[8], stdv[8], noisy[8], p[8];
        float mx = -1e30f;
#pragma unroll
        for (int e = 0; e < 8; e++) {
            clean[e] = accg[e];
            float xn = accn[e];
            float sp = (xn > 0.f) ? (xn + log1pf(expf(-xn))) : log1pf(expf(xn));
            stdv[e] = sp + 0.01f;
            noisy[e] = clean[e] + noise[(size_t)b * 8 + e] * stdv[e];
            mx = fmaxf(mx, noisy[e]);
        }
        float se = 0.f;
#pragma unroll
        for (int e = 0; e < 8; e++) { p[e] = expf(noisy[e] - mx); se += p[e]; }
        float inv = 1.f / se;
#pragma unroll
        for (int e = 0; e < 8; e++) p[e] *= inv;

        int i0 = -1, i1 = -1;
        float p0 = -1e30f, p1v = -1e30f, p2v = -1e30f;
#pragma unroll
        for (int e = 0; e < 8; e++) if (p[e] > p0) { p0 = p[e]; i0 = e; }
#pragma unroll
        for (int e = 0; e < 8; e++) if (e != i0 && p[e] > p1v) { p1v = p[e]; i1 = e; }
#pragma unroll
        for (int e = 0; e < 8; e++) if (e != i0 && e != i1 && p[e] > p2v) { p2v = p[e]; }

        float den = p0 + p1v + 1e-6f;
        float g0 = p0 / den, g1 = p1v / den;
        eidx[2 * b] = i0; eidx[2 * b + 1] = i1;
        gval[2 * b] = g0; gval[2 * b + 1] = g1;

        const float is2 = 0.70710678118654752440f;
#pragma unroll
        for (int e = 0; e < 8; e++) {
            float pin  = 0.5f * (1.f + erff((clean[e] - p2v) / stdv[e] * is2));
            float pout = 0.5f * (1.f + erff((clean[e] - p1v) / stdv[e] * is2));
            s_load[w][e] = (noisy[e] > p2v) ? pin : pout;
            s_imp[w][e]  = (e == i0) ? g0 : (e == i1) ? g1 : 0.f;
            s_cnt[w][e]  = (e == i0 || e == i1) ? 1.f : 0.f;
        }
    }
    __syncthreads();
    if (t < 8) {
        float sl = 0.f, si = 0.f, sc = 0.f;
#pragma unroll
        for (int ww = 0; ww < 4; ww++) {
            sl += s_load[ww][t]; si += s_imp[ww][t]; sc += s_cnt[ww][t];
        }
        load_p[blockIdx.x * 8 + t] = sl;
        imp_p [blockIdx.x * 8 + t] = si;
        cnt_p [blockIdx.x * 8 + t] = sc;
    }
}

__global__ void scan_loss_kernel(const float* __restrict__ cnt_p, const float* __restrict__ imp_p,
                                 const float* __restrict__ load_p,
                                 int* __restrict__ counts, int* __restrict__ off,
                                 int* __restrict__ toff, float* __restrict__ out_loss)
{
    __shared__ float s_c[64], s_i[64], s_l[64];
    __shared__ float f_c[8], f_i[8], f_l[8];
    int t = threadIdx.x;
    int e = t & 7, g = t >> 3;
    float sc = 0.f, si = 0.f, sl = 0.f;
    for (int blk = g * 128; blk < (g + 1) * 128; blk++) {
        sc += cnt_p[blk * 8 + e];
        si += imp_p[blk * 8 + e];
        sl += load_p[blk * 8 + e];
    }
    s_c[t] = sc; s_i[t] = si; s_l[t] = sl;
    __syncthreads();
    if (t < 8) {
        float c = 0.f, i = 0.f, l = 0.f;
        for (int gg = 0; gg < 8; gg++) { c += s_c[gg * 8 + t]; i += s_i[gg * 8 + t]; l += s_l[gg * 8 + t]; }
        f_c[t] = c; f_i[t] = i; f_l[t] = l;
        counts[t] = (int)(c + 0.5f);
    }
    __syncthreads();
    if (t == 0) {
        int o = 0, to = 0;
        off[0] = 0; toff[0] = 0;
        for (int ee = 0; ee < 8; ee++) {
            int c = (int)(f_c[ee] + 0.5f);
            o += c; off[ee + 1] = o;
            to += (c + 31) / 32; toff[ee + 1] = to;
        }
        float mi = 0.f, ml = 0.f;
        for (int ee = 0; ee < 8; ee++) { mi += f_i[ee]; ml += f_l[ee]; }
        mi *= 0.125f; ml *= 0.125f;
        float vi = 0.f, vl = 0.f;
        for (int ee = 0; ee < 8; ee++) {
            float di = f_i[ee] - mi; vi += di * di;
            float dl = f_l[ee] - ml; vl += dl * dl;
        }
        vi /= 7.f; vl /= 7.f;
        out_loss[0] = (vi / (mi * mi + 1e-10f) + vl / (ml * ml + 1e-10f)) * 0.01f;
    }
}

// ---------------- deterministic fill: counting sort, single block ----------------
__global__ __launch_bounds__(256) void fill_kernel(
    const int* __restrict__ eidx, const int* __restrict__ off, int* __restrict__ rowlist)
{
    __shared__ int hist[256][8];
    __shared__ int off_s[8];
    int t = threadIdx.x;
    if (t < 8) off_s[t] = off[t];
    int base = t * 32;
    int le[32];
    int c[8];
#pragma unroll
    for (int e = 0; e < 8; e++) c[e] = 0;
#pragma unroll
    for (int j = 0; j < 32; j++) {
        int ev = eidx[base + j];
        le[j] = ev;
#pragma unroll
        for (int e = 0; e < 8; e++) c[e] += (ev == e) ? 1 : 0;
    }
#pragma unroll
    for (int e = 0; e < 8; e++) hist[t][e] = c[e];
    __syncthreads();
    if (t < 8) {
        int run = 0;
        for (int i = 0; i < 256; i++) { int v = hist[i][t]; hist[i][t] = run; run += v; }
    }
    __syncthreads();
#pragma unroll
    for (int j = 0; j < 32; j++) {
        int ev = le[j];
        int p = hist[t][ev];
        hist[t][ev] = p + 1;
        rowlist[off_s[ev] + p] = base + j;
    }
}

// ---------------- prep: features fp32 -> bf16, p-stream concat ----------------
__global__ __launch_bounds__(256) void prep_feat_kernel(
    const float* __restrict__ sf, const float* __restrict__ of,
    const float* __restrict__ ppf, const float* __restrict__ pvf,
    unsigned short* __restrict__ Fb)
{
    int idx = blockIdx.x * 256 + threadIdx.x;
    int flat = idx * 8;
    int strm = flat >> 22;
    int rem = flat & 4194303;
    int b = rem >> 10;
    int k = rem & 1023;
    const float* src;
    if (strm == 0)      src = sf  + (size_t)b * 1024 + k;
    else if (strm == 1) src = of  + (size_t)b * 1024 + k;
    else src = (k < 512) ? (ppf + (size_t)b * 512 + k) : (pvf + (size_t)b * 512 + (k - 512));
    float4 f0 = *(const float4*)src;
    float4 f1 = *(const float4*)(src + 4);
    uint4 o;
    o.x = (unsigned)f2bf(f0.x) | ((unsigned)f2bf(f0.y) << 16);
    o.y = (unsigned)f2bf(f0.z) | ((unsigned)f2bf(f0.w) << 16);
    o.z = (unsigned)f2bf(f1.x) | ((unsigned)f2bf(f1.y) << 16);
    o.w = (unsigned)f2bf(f1.z) | ((unsigned)f2bf(f1.w) << 16);
    *(uint4*)(Fb + flat) = o;
}

// ---------------- prep: W [e][k][c] -> Wt [e'][c][k] bf16 ----------------
__global__ __launch_bounds__(256) void prep_w_kernel(
    const float* __restrict__ Ws, const float* __restrict__ Wo, const float* __restrict__ Wp,
    unsigned short* __restrict__ Wt)
{
    __shared__ unsigned short LT[64][68];
    int bid = blockIdx.x;
    int ep = bid >> 6;
    int rem = bid & 63;
    int k0 = (rem >> 2) * 64;
    int c0 = (rem & 3) * 64;
    int strm = ep >> 3, e = ep & 7;
    const float* W = ((strm == 0) ? Ws : (strm == 1) ? Wo : Wp) + (size_t)e * (1024 * 256);

    int t = threadIdx.x;
    int c_l = t & 63;
    int kb = t >> 6;
#pragma unroll
    for (int r = 0; r < 16; r++) {
        int k_l = r * 4 + kb;
        LT[c_l][k_l] = f2bf(W[(size_t)(k0 + k_l) * 256 + c0 + c_l]);
    }
    __syncthreads();

    int cw = t >> 2, kq = t & 3;
    unsigned short* dst_row = Wt + (size_t)ep * 262144 + (size_t)(c0 + cw) * 1024 + k0;
#pragma unroll
    for (int p = 0; p < 2; p++) {
        int kqp = kq + p * 4;
        ushort4 a = *(ushort4*)&LT[cw][kqp * 8];
        ushort4 b = *(ushort4*)&LT[cw][kqp * 8 + 4];
        uint4 o;
        o.x = (unsigned)a.x | ((unsigned)a.y << 16);
        o.y = (unsigned)a.z | ((unsigned)a.w << 16);
        o.z = (unsigned)b.x | ((unsigned)b.y << 16);
        o.w = (unsigned)b.z | ((unsigned)b.w << 16);
        *(uint4*)(dst_row + kqp * 8) = o;
    }
}

// ---------------- MFMA combine: BM=32, BN=256, BK=64, double-buffered ----------------
__global__ __launch_bounds__(256) void combine_mfma_kernel(
    const unsigned short* __restrict__ Fb, const unsigned short* __restrict__ Wt,
    const int* __restrict__ counts, const int* __restrict__ off, const int* __restrict__ toff,
    const int* __restrict__ rowlist, const float* __restrict__ gval,
    float* __restrict__ out)
{
    int bid = blockIdx.x;
    int strm = blockIdx.z;
    if (bid >= toff[8]) return;
    int e = 0;
    while (bid >= toff[e + 1]) e++;
    int tm = bid - toff[e];
    int cnt = counts[e];
    int obase = off[e];
    int ep = strm * 8 + e;

    __shared__ unsigned short A_lds[2][32 * 64];
    __shared__ unsigned short B_lds[2][256 * 64];
    __shared__ int rows_s[32];
    __shared__ float gate_s[32];
    __shared__ float s_red[32][4];

    int t = threadIdx.x;
    int l = t & 63, w = t >> 6;

    if (t < 32) {
        int m = tm * 32 + t;
        if (m < cnt) {
            int pid = rowlist[obase + m];
            rows_s[t] = pid >> 1;
            gate_s[t] = gval[pid];
        } else {
            rows_s[t] = 0;
            gate_s[t] = 0.f;
        }
    }
    __syncthreads();

    int sm = t >> 3;
    int ss = t & 7;
    int arow = rows_s[sm];
    const unsigned short* asrc = Fb + (size_t)strm * 4194304 + (size_t)arow * 1024 + ss * 8;
    const unsigned short* bsrc = Wt + (size_t)ep * 262144 + (size_t)sm * 1024 + ss * 8;
    int aw = sm * 64 + ((ss ^ (sm & 7)) * 8);
    int bw = (ss ^ (sm & 7)) * 8;

    // prologue: stage tile 0 into buf 0
    {
        uint4 ra = *(const uint4*)(asrc);
        uint4 rb[8];
#pragma unroll
        for (int q = 0; q < 8; q++) rb[q] = *(const uint4*)(bsrc + q * 32768);
        *(uint4*)&A_lds[0][aw] = ra;
#pragma unroll
        for (int q = 0; q < 8; q++) *(uint4*)&B_lds[0][(sm + q * 32) * 64 + bw] = rb[q];
    }

    f32x4 acc[2][4];
#pragma unroll
    for (int i = 0; i < 2; i++)
#pragma unroll
        for (int j = 0; j < 4; j++)
#pragma unroll
            for (int r = 0; r < 4; r++) acc[i][j][r] = 0.f;

    int g = l >> 4;
    int axor = l & 7;

    for (int kt = 0; kt < 16; kt++) {
        int cur = kt & 1;
        uint4 ra; uint4 rb[8];
        if (kt < 15) {
            int ko = (kt + 1) * 64;
            ra = *(const uint4*)(asrc + ko);
#pragma unroll
            for (int q = 0; q < 8; q++) rb[q] = *(const uint4*)(bsrc + q * 32768 + ko);
        }
        __syncthreads();   // buf[cur] ready; prior reads of buf[cur^1] done
        if (kt < 15) {
            *(uint4*)&A_lds[cur ^ 1][aw] = ra;
#pragma unroll
            for (int q = 0; q < 8; q++) *(uint4*)&B_lds[cur ^ 1][(sm + q * 32) * 64 + bw] = rb[q];
        }
#pragma unroll
        for (int kw = 0; kw < 2; kw++) {
            int slot = ((kw * 4 + g) ^ axor) * 8;
            bf16x8 af[2], bf[4];
#pragma unroll
            for (int i = 0; i < 2; i++)
                af[i] = *(const bf16x8*)&A_lds[cur][((l & 15) + i * 16) * 64 + slot];
#pragma unroll
            for (int j = 0; j < 4; j++) {
                int c = w * 64 + j * 16 + (l & 15);
                bf[j] = *(const bf16x8*)&B_lds[cur][c * 64 + slot];
            }
#pragma unroll
            for (int i = 0; i < 2; i++)
#pragma unroll
                for (int j = 0; j < 4; j++)
                    acc[i][j] = __builtin_amdgcn_mfma_f32_16x16x32_bf16(af[i], bf[j], acc[i][j], 0, 0, 0);
        }
    }

    // epilogue: softmax over 256 cols per row, gate-scale, atomic add
    float* comb = out + (size_t)strm * (NB * CC);
    float rmx[2][4], scale[2][4];

#pragma unroll
    for (int i = 0; i < 2; i++)
#pragma unroll
        for (int r = 0; r < 4; r++) {
            float mx = -1e30f;
#pragma unroll
            for (int j = 0; j < 4; j++) mx = fmaxf(mx, acc[i][j][r]);
#pragma unroll
            for (int s = 1; s < 16; s <<= 1) mx = fmaxf(mx, __shfl_xor(mx, s));
            if ((l & 15) == 0) s_red[i * 16 + g * 4 + r][w] = mx;
        }
    __syncthreads();
#pragma unroll
    for (int i = 0; i < 2; i++)
#pragma unroll
        for (int r = 0; r < 4; r++) {
            int row = i * 16 + g * 4 + r;
            rmx[i][r] = fmaxf(fmaxf(s_red[row][0], s_red[row][1]), fmaxf(s_red[row][2], s_red[row][3]));
        }
    __syncthreads();
#pragma unroll
    for (int i = 0; i < 2; i++)
#pragma unroll
        for (int r = 0; r < 4; r++) {
            float se = 0.f;
#pragma unroll
            for (int j = 0; j < 4; j++) {
                float v = __expf(acc[i][j][r] - rmx[i][r]);
                acc[i][j][r] = v;
                se += v;
            }
#pragma unroll
            for (int s = 1; s < 16; s <<= 1) se += __shfl_xor(se, s);
            if ((l & 15) == 0) s_red[i * 16 + g * 4 + r][w] = se;
        }
    __syncthreads();
#pragma unroll
    for (int i = 0; i < 2; i++)
#pragma unroll
        for (int r = 0; r < 4; r++) {
            int row = i * 16 + g * 4 + r;
            float tot = s_red[row][0] + s_red[row][1] + s_red[row][2] + s_red[row][3];
            scale[i][r] = gate_s[row] / tot;
        }
#pragma unroll
    for (int i = 0; i < 2; i++)
#pragma unroll
        for (int r = 0; r < 4; r++) {
            int row = i * 16 + g * 4 + r;
            int row_g = rows_s[row];
            float sc = scale[i][r];
#pragma unroll
            for (int j = 0; j < 4; j++) {
                int col = w * 64 + j * 16 + (l & 15);
                atomicAdd(comb + (size_t)row_g * 256 + col, acc[i][j][r] * sc);
            }
        }
}

// ---------------- fallback fp32 combine ----------------
__global__ __launch_bounds__(256) void combine_kernel(
    const float* __restrict__ sf, const float* __restrict__ of,
    const float* __restrict__ ppf, const float* __restrict__ pvf,
    const float* __restrict__ Ws, const float* __restrict__ Wo, const float* __restrict__ Wp,
    const int* __restrict__ counts, const int* __restrict__ off, const int* __restrict__ toff,
    const int* __restrict__ rowlist, const float* __restrict__ gval,
    float* __restrict__ out)
{
    int bid = blockIdx.x;
    int strm = blockIdx.z;
    if (bid >= toff[8]) return;
    int e = 0;
    while (bid >= toff[e + 1]) e++;
    int tm = bid - toff[e];
    int cnt = counts[e];
    int obase = off[e];

    __shared__ float As[32][36];
    __shared__ float Bs[32][256];
    __shared__ int rows_s[32];
    __shared__ float gate_s[32];

    int t = threadIdx.x;
    if (t < 32) {
        int m = tm * 32 + t;
        if (m < cnt) {
            int pid = rowlist[obase + m];
            rows_s[t] = pid >> 1;
            gate_s[t] = gval[pid];
        } else {
            rows_s[t] = -1;
            gate_s[t] = 0.f;
        }
    }
    __syncthreads();

    const float* W = ((strm == 0) ? Ws : (strm == 1) ? Wo : Wp) + (size_t)e * DD * CC;
    float acc[2][16];
#pragma unroll
    for (int i = 0; i < 2; i++)
#pragma unroll
        for (int j = 0; j < 16; j++) acc[i][j] = 0.f;

    int tx = t & 15, ty = t >> 4;
    int r_st = t >> 3, d4 = t & 7;
    int row_st = rows_s[r_st];

    for (int k0 = 0; k0 < DD; k0 += 32) {
        float4 v = make_float4(0.f, 0.f, 0.f, 0.f);
        if (row_st >= 0) {
            int d = k0 + d4 * 4;
            if (strm == 0)      v = *(const float4*)(sf + (size_t)row_st * DD + d);
            else if (strm == 1) v = *(const float4*)(of + (size_t)row_st * DD + d);
            else v = (d < 512) ? *(const float4*)(ppf + (size_t)row_st * 512 + d)
                               : *(const float4*)(pvf + (size_t)row_st * 512 + (d - 512));
        }
        As[d4 * 4 + 0][r_st] = v.x;
        As[d4 * 4 + 1][r_st] = v.y;
        As[d4 * 4 + 2][r_st] = v.z;
        As[d4 * 4 + 3][r_st] = v.w;
#pragma unroll
        for (int j = 0; j < 8; j++) {
            int vv = t + 256 * j;
            int k = vv >> 6, c4 = vv & 63;
            *(float4*)&Bs[k][c4 * 4] = *(const float4*)&W[(size_t)(k0 + k) * CC + c4 * 4];
        }
        __syncthreads();

#pragma unroll
        for (int k = 0; k < 32; k++) {
            float2 a = *(float2*)&As[k][ty * 2];
#pragma unroll
            for (int jj = 0; jj < 4; jj++) {
                float4 bb = *(float4*)&Bs[k][jj * 64 + tx * 4];
                acc[0][jj * 4 + 0] += a.x * bb.x;
                acc[0][jj * 4 + 1] += a.x * bb.y;
                acc[0][jj * 4 + 2] += a.x * bb.z;
                acc[0][jj * 4 + 3] += a.x * bb.w;
                acc[1][jj * 4 + 0] += a.y * bb.x;
                acc[1][jj * 4 + 1] += a.y * bb.y;
                acc[1][jj * 4 + 2] += a.y * bb.z;
                acc[1][jj * 4 + 3] += a.y * bb.w;
            }
        }
        __syncthreads();
    }

    float* comb = out + (size_t)strm * (NB * CC);
#pragma unroll
    for (int i = 0; i < 2; i++) {
        int r = ty * 2 + i;
        int row = rows_s[r];
        if (row < 0) continue;
        float mx = -1e30f;
#pragma unroll
        for (int j = 0; j < 16; j++) mx = fmaxf(mx, acc[i][j]);
        for (int s = 1; s < 16; s <<= 1) mx = fmaxf(mx, __shfl_xor(mx, s, 16));
        float se = 0.f;
#pragma unroll
        for (int j = 0; j < 16; j++) { acc[i][j] = expf(acc[i][j] - mx); se += acc[i][j]; }
        for (int s = 1; s < 16; s <<= 1) se += __shfl_xor(se, s, 16);
        float scale = gate_s[r] / se;
#pragma unroll
        for (int jj = 0; jj < 4; jj++)
#pragma unroll
            for (int jo = 0; jo < 4; jo++) {
                int col = jj * 64 + tx * 4 + jo;
                atomicAdd(comb + (size_t)row * CC + col, acc[i][jj * 4 + jo] * scale);
            }
    }
}

__global__ void log_kernel(float* __restrict__ out, int n4)
{
    int i = blockIdx.x * 256 + threadIdx.x;
    if (i >= n4) return;
    float4 v = *(float4*)(out + (size_t)i * 4);
    const float EPSL = 2.2204460492503131e-16f;
    v.x = logf(v.x == 0.f ? EPSL : v.x);
    v.y = logf(v.y == 0.f ? EPSL : v.y);
    v.z = logf(v.z == 0.f ? EPSL : v.z);
    v.w = logf(v.w == 0.f ? EPSL : v.w);
    *(float4*)(out + (size_t)i * 4) = v;
}

extern "C" void kernel_launch(void* const* d_in, const int* in_sizes, int n_in,
                              void* d_out, int out_size, void* d_ws, size_t ws_size,
                              hipStream_t stream) {
    (void)in_sizes; (void)n_in;
    const float* sf    = (const float*)d_in[0];
    const float* of    = (const float*)d_in[1];
    const float* ppf   = (const float*)d_in[2];
    const float* pvf   = (const float*)d_in[3];
    const float* noise = (const float*)d_in[4];
    const float* wg    = (const float*)d_in[5];
    const float* wn    = (const float*)d_in[6];
    const float* Ws    = (const float*)d_in[7];
    const float* Wo    = (const float*)d_in[8];
    const float* Wp    = (const float*)d_in[9];
    float* out = (float*)d_out;

    char* ws = (char*)d_ws;
    int*   off     = (int*)(ws + 64);
    int*   toff    = (int*)(ws + 104);
    int*   counts  = (int*)(ws + 144);
    float* gval    = (float*)(ws + 256);
    int*   eidx    = (int*)(ws + 33024);
    int*   rowlist = (int*)(ws + 65792);
    float* cnt_p   = (float*)(ws + 98560);
    float* imp_p   = (float*)(ws + 131328);
    float* load_p  = (float*)(ws + 164096);
    unsigned short* Wt = (unsigned short*)(ws + WT_OFF);
    unsigned short* Fb = (unsigned short*)(ws + FB_OFF);

    bool fast = ws_size >= WS_FAST_NEED;

    hipMemsetAsync(d_out, 0, (size_t)out_size * sizeof(float), stream);

    if (fast) {
        prep_feat_kernel<<<6144, 256, 0, stream>>>(sf, of, ppf, pvf, Fb);
        prep_w_kernel<<<1536, 256, 0, stream>>>(Ws, Wo, Wp, Wt);
    }

    gating_kernel<<<NGBLK, 256, 0, stream>>>(sf, noise, wg, wn, gval, eidx, cnt_p, imp_p, load_p);
    scan_loss_kernel<<<1, 64, 0, stream>>>(cnt_p, imp_p, load_p, counts, off, toff, out + (out_size - 1));
    fill_kernel<<<1, 256, 0, stream>>>(eidx, off, rowlist);

    if (fast) {
        combine_mfma_kernel<<<dim3(264, 1, 3), 256, 0, stream>>>(
            Fb, Wt, counts, off, toff, rowlist, gval, out);
    } else {
        combine_kernel<<<dim3(2 * NB / 32 + 8, 1, 3), 256, 0, stream>>>(
            sf, of, ppf, pvf, Ws, Wo, Wp, counts, off, toff, rowlist, gval, out);
    }

    int n4 = (out_size - 1) / 4;
    log_kernel<<<(n4 + 255) / 256, 256, 0, stream>>>(out, n4);
}

// Round 5
// 331.774 us; speedup vs baseline: 2.5408x; 1.0531x over previous
//
#include <hip/hip_runtime.h>
#include <math.h>

#define NB 4096
#define DD 1024
#define CC 256
#define NE 8
#define NGBLK 1024

typedef short bf16x8 __attribute__((ext_vector_type(8)));
typedef float f32x4 __attribute__((ext_vector_type(4)));

// ws layout (bytes):
//   64: off[9] | 104: toff[9] | 144: counts[8]
//   256:    gval f32[8192] | 33024: eidx int[8192] | 65792: rowlist int[8192]
//   98560:  cnt_p f32[NGBLK*8] | 131328: imp_p | 164096: load_p
//   256KB:  Wt bf16 [24][256][1024]          (12.58 MB)   -- fast path
//   13MB:   partial f32 [3][8224][256]       (25.26 MB)   -- fast path
#define WT_OFF   262144ull
#define PART_OFF 13631488ull
#define PART_ROWS 8224
#define WS_FAST_NEED (41943040ull)

__device__ __forceinline__ unsigned short f2bf(float f) {
    union { float f; unsigned u; } v; v.f = f;
    unsigned x = v.u;
    return (unsigned short)((x + 0x7FFFu + ((x >> 16) & 1u)) >> 16);
}

// ---------------- gating ----------------
__global__ __launch_bounds__(256) void gating_kernel(
    const float* __restrict__ sf, const float* __restrict__ noise,
    const float* __restrict__ wg, const float* __restrict__ wn,
    float* __restrict__ gval, int* __restrict__ eidx,
    float* __restrict__ cnt_p, float* __restrict__ imp_p, float* __restrict__ load_p)
{
    int t = threadIdx.x;
    int lane = t & 63;
    int w = t >> 6;
    int b = blockIdx.x * 4 + w;
    const float* x = sf + (size_t)b * DD;

    float accg[8], accn[8];
#pragma unroll
    for (int e = 0; e < 8; e++) { accg[e] = 0.f; accn[e] = 0.f; }

#pragma unroll
    for (int q = 0; q < 16; q++) {
        int d = q * 64 + lane;
        float xs = x[d];
        float4 g0 = *(const float4*)(wg + (size_t)d * 8);
        float4 g1 = *(const float4*)(wg + (size_t)d * 8 + 4);
        float4 n0 = *(const float4*)(wn + (size_t)d * 8);
        float4 n1 = *(const float4*)(wn + (size_t)d * 8 + 4);
        accg[0] += xs * g0.x; accg[1] += xs * g0.y; accg[2] += xs * g0.z; accg[3] += xs * g0.w;
        accg[4] += xs * g1.x; accg[5] += xs * g1.y; accg[6] += xs * g1.z; accg[7] += xs * g1.w;
        accn[0] += xs * n0.x; accn[1] += xs * n0.y; accn[2] += xs * n0.z; accn[3] += xs * n0.w;
        accn[4] += xs * n1.x; accn[5] += xs * n1.y; accn[6] += xs * n1.z; accn[7] += xs * n1.w;
    }
#pragma unroll
    for (int e = 0; e < 8; e++) {
        for (int s = 1; s < 64; s <<= 1) {
            accg[e] += __shfl_xor(accg[e], s);
            accn[e] += __shfl_xor(accn[e], s);
        }
    }

    __shared__ float s_load[4][8], s_imp[4][8], s_cnt[4][8];

    if (lane == 0) {
        float clean[8], stdv[8], noisy[8], p[8];
        float mx = -1e30f;
#pragma unroll
        for (int e = 0; e < 8; e++) {
            clean[e] = accg[e];
            float xn = accn[e];
            float sp = (xn > 0.f) ? (xn + log1pf(expf(-xn))) : log1pf(expf(xn));
            stdv[e] = sp + 0.01f;
            noisy[e] = clean[e] + noise[(size_t)b * 8 + e] * stdv[e];
            mx = fmaxf(mx, noisy[e]);
        }
        float se = 0.f;
#pragma unroll
        for (int e = 0; e < 8; e++) { p[e] = expf(noisy[e] - mx); se += p[e]; }
        float inv = 1.f / se;
#pragma unroll
        for (int e = 0; e < 8; e++) p[e] *= inv;

        int i0 = -1, i1 = -1;
        float p0 = -1e30f, p1v = -1e30f, p2v = -1e30f;
#pragma unroll
        for (int e = 0; e < 8; e++) if (p[e] > p0) { p0 = p[e]; i0 = e; }
#pragma unroll
        for (int e = 0; e < 8; e++) if (e != i0 && p[e] > p1v) { p1v = p[e]; i1 = e; }
#pragma unroll
        for (int e = 0; e < 8; e++) if (e != i0 && e != i1 && p[e] > p2v) { p2v = p[e]; }

        float den = p0 + p1v + 1e-6f;
        float g0 = p0 / den, g1 = p1v / den;
        eidx[2 * b] = i0; eidx[2 * b + 1] = i1;
        gval[2 * b] = g0; gval[2 * b + 1] = g1;

        const float is2 = 0.70710678118654752440f;
#pragma unroll
        for (int e = 0; e < 8; e++) {
            float pin  = 0.5f * (1.f + erff((clean[e] - p2v) / stdv[e] * is2));
            float pout = 0.5f * (1.f + erff((clean[e] - p1v) / stdv[e] * is2));
            s_load[w][e] = (noisy[e] > p2v) ? pin : pout;
            s_imp[w][e]  = (e == i0) ? g0 : (e == i1) ? g1 : 0.f;
            s_cnt[w][e]  = (e == i0 || e == i1) ? 1.f : 0.f;
        }
    }
    __syncthreads();
    if (t < 8) {
        float sl = 0.f, si = 0.f, sc = 0.f;
#pragma unroll
        for (int ww = 0; ww < 4; ww++) {
            sl += s_load[ww][t]; si += s_imp[ww][t]; sc += s_cnt[ww][t];
        }
        load_p[blockIdx.x * 8 + t] = sl;
        imp_p [blockIdx.x * 8 + t] = si;
        cnt_p [blockIdx.x * 8 + t] = sc;
    }
}

__global__ void scan_loss_kernel(const float* __restrict__ cnt_p, const float* __restrict__ imp_p,
                                 const float* __restrict__ load_p,
                                 int* __restrict__ counts, int* __restrict__ off,
                                 int* __restrict__ toff, float* __restrict__ out_loss)
{
    __shared__ float s_c[64], s_i[64], s_l[64];
    __shared__ float f_c[8], f_i[8], f_l[8];
    int t = threadIdx.x;
    int e = t & 7, g = t >> 3;
    float sc = 0.f, si = 0.f, sl = 0.f;
    for (int blk = g * 128; blk < (g + 1) * 128; blk++) {
        sc += cnt_p[blk * 8 + e];
        si += imp_p[blk * 8 + e];
        sl += load_p[blk * 8 + e];
    }
    s_c[t] = sc; s_i[t] = si; s_l[t] = sl;
    __syncthreads();
    if (t < 8) {
        float c = 0.f, i = 0.f, l = 0.f;
        for (int gg = 0; gg < 8; gg++) { c += s_c[gg * 8 + t]; i += s_i[gg * 8 + t]; l += s_l[gg * 8 + t]; }
        f_c[t] = c; f_i[t] = i; f_l[t] = l;
        counts[t] = (int)(c + 0.5f);
    }
    __syncthreads();
    if (t == 0) {
        int o = 0, to = 0;
        off[0] = 0; toff[0] = 0;
        for (int ee = 0; ee < 8; ee++) {
            int c = (int)(f_c[ee] + 0.5f);
            o += c; off[ee + 1] = o;
            to += (c + 31) / 32; toff[ee + 1] = to;
        }
        float mi = 0.f, ml = 0.f;
        for (int ee = 0; ee < 8; ee++) { mi += f_i[ee]; ml += f_l[ee]; }
        mi *= 0.125f; ml *= 0.125f;
        float vi = 0.f, vl = 0.f;
        for (int ee = 0; ee < 8; ee++) {
            float di = f_i[ee] - mi; vi += di * di;
            float dl = f_l[ee] - ml; vl += dl * dl;
        }
        vi /= 7.f; vl /= 7.f;
        out_loss[0] = (vi / (mi * mi + 1e-10f) + vl / (ml * ml + 1e-10f)) * 0.01f;
    }
}

// ---------------- deterministic fill: counting sort, single block ----------------
__global__ __launch_bounds__(256) void fill_kernel(
    const int* __restrict__ eidx, const int* __restrict__ off, int* __restrict__ rowlist)
{
    __shared__ int hist[256][8];
    __shared__ int off_s[8];
    int t = threadIdx.x;
    if (t < 8) off_s[t] = off[t];
    int base = t * 32;
    int le[32];
    int c[8];
#pragma unroll
    for (int e = 0; e < 8; e++) c[e] = 0;
#pragma unroll
    for (int j = 0; j < 32; j++) {
        int ev = eidx[base + j];
        le[j] = ev;
#pragma unroll
        for (int e = 0; e < 8; e++) c[e] += (ev == e) ? 1 : 0;
    }
#pragma unroll
    for (int e = 0; e < 8; e++) hist[t][e] = c[e];
    __syncthreads();
    if (t < 8) {
        int run = 0;
        for (int i = 0; i < 256; i++) { int v = hist[i][t]; hist[i][t] = run; run += v; }
    }
    __syncthreads();
#pragma unroll
    for (int j = 0; j < 32; j++) {
        int ev = le[j];
        int p = hist[t][ev];
        hist[t][ev] = p + 1;
        rowlist[off_s[ev] + p] = base + j;
    }
}

// ---------------- prep: W [e][k][c] -> Wt [e'][c][k] bf16 ----------------
__global__ __launch_bounds__(256) void prep_w_kernel(
    const float* __restrict__ Ws, const float* __restrict__ Wo, const float* __restrict__ Wp,
    unsigned short* __restrict__ Wt)
{
    __shared__ unsigned short LT[64][68];
    int bid = blockIdx.x;
    int ep = bid >> 6;
    int rem = bid & 63;
    int k0 = (rem >> 2) * 64;
    int c0 = (rem & 3) * 64;
    int strm = ep >> 3, e = ep & 7;
    const float* W = ((strm == 0) ? Ws : (strm == 1) ? Wo : Wp) + (size_t)e * (1024 * 256);

    int t = threadIdx.x;
    int c_l = t & 63;
    int kb = t >> 6;
#pragma unroll
    for (int r = 0; r < 16; r++) {
        int k_l = r * 4 + kb;
        LT[c_l][k_l] = f2bf(W[(size_t)(k0 + k_l) * 256 + c0 + c_l]);
    }
    __syncthreads();

    int cw = t >> 2, kq = t & 3;
    unsigned short* dst_row = Wt + (size_t)ep * 262144 + (size_t)(c0 + cw) * 1024 + k0;
#pragma unroll
    for (int p = 0; p < 2; p++) {
        int kqp = kq + p * 4;
        ushort4 a = *(ushort4*)&LT[cw][kqp * 8];
        ushort4 b = *(ushort4*)&LT[cw][kqp * 8 + 4];
        uint4 o;
        o.x = (unsigned)a.x | ((unsigned)a.y << 16);
        o.y = (unsigned)a.z | ((unsigned)a.w << 16);
        o.z = (unsigned)b.x | ((unsigned)b.y << 16);
        o.w = (unsigned)b.z | ((unsigned)b.w << 16);
        *(uint4*)(dst_row + kqp * 8) = o;
    }
}

// ---------------- MFMA combine: BM=32, BN=256, BK=64, dbuf, no atomics ----------------
__global__ __launch_bounds__(256) void combine_mfma_kernel(
    const float* __restrict__ sf, const float* __restrict__ of,
    const float* __restrict__ ppf, const float* __restrict__ pvf,
    const unsigned short* __restrict__ Wt,
    const int* __restrict__ counts, const int* __restrict__ off, const int* __restrict__ toff,
    const int* __restrict__ rowlist, const float* __restrict__ gval,
    float* __restrict__ partial)
{
    int bid = blockIdx.x;
    int strm = blockIdx.z;
    if (bid >= toff[8]) return;
    int e = 0;
    while (bid >= toff[e + 1]) e++;
    int tm = bid - toff[e];
    int cnt = counts[e];
    int obase = off[e];
    int ep = strm * 8 + e;

    __shared__ unsigned short A_lds[2][32 * 64];
    __shared__ unsigned short B_lds[2][256 * 64];
    __shared__ int rows_s[32];
    __shared__ int pid_s[32];
    __shared__ float gate_s[32];
    __shared__ float s_red[32][4];

    int t = threadIdx.x;
    int l = t & 63, w = t >> 6;

    if (t < 32) {
        int m = tm * 32 + t;
        if (m < cnt) {
            int pid = rowlist[obase + m];
            rows_s[t] = pid >> 1;
            pid_s[t] = pid;
            gate_s[t] = gval[pid];
        } else {
            rows_s[t] = 0;
            pid_s[t] = 8192;     // dump row (benign 0-stores, never read)
            gate_s[t] = 0.f;
        }
    }
    __syncthreads();

    int sm = t >> 3;             // A/B row index 0..31
    int ss = t & 7;              // 16B slot 0..7 -> k chunk ss*8..ss*8+7
    int arow = rows_s[sm];
    // A source (fp32, converted inline); stream-dependent base
    const float* a01 = (strm == 0) ? (sf + (size_t)arow * DD) : (of + (size_t)arow * DD);
    const float* app = ppf + (size_t)arow * 512;
    const float* apv = pvf + (size_t)arow * 512;
    const unsigned short* bsrc = Wt + (size_t)ep * 262144 + (size_t)sm * 1024 + ss * 8;
    int aw = sm * 64 + ((ss ^ (sm & 7)) * 8);
    int bw = (ss ^ (sm & 7)) * 8;

#define LOAD_A_CHUNK(ko, dst)                                              \
    {                                                                      \
        int kk = (ko) + ss * 8;                                            \
        const float* s_;                                                   \
        if (strm != 2) s_ = a01 + kk;                                      \
        else s_ = (kk < 512) ? (app + kk) : (apv + (kk - 512));            \
        float4 f0 = *(const float4*)s_;                                    \
        float4 f1 = *(const float4*)(s_ + 4);                              \
        dst.x = (unsigned)f2bf(f0.x) | ((unsigned)f2bf(f0.y) << 16);       \
        dst.y = (unsigned)f2bf(f0.z) | ((unsigned)f2bf(f0.w) << 16);       \
        dst.z = (unsigned)f2bf(f1.x) | ((unsigned)f2bf(f1.y) << 16);       \
        dst.w = (unsigned)f2bf(f1.z) | ((unsigned)f2bf(f1.w) << 16);       \
    }

    // prologue: stage tile 0 into buf 0
    {
        uint4 ra; LOAD_A_CHUNK(0, ra);
        uint4 rb[8];
#pragma unroll
        for (int q = 0; q < 8; q++) rb[q] = *(const uint4*)(bsrc + q * 32768);
        *(uint4*)&A_lds[0][aw] = ra;
#pragma unroll
        for (int q = 0; q < 8; q++) *(uint4*)&B_lds[0][(sm + q * 32) * 64 + bw] = rb[q];
    }

    f32x4 acc[2][4];
#pragma unroll
    for (int i = 0; i < 2; i++)
#pragma unroll
        for (int j = 0; j < 4; j++)
#pragma unroll
            for (int r = 0; r < 4; r++) acc[i][j][r] = 0.f;

    int g = l >> 4;
    int axor = l & 7;

    for (int kt = 0; kt < 16; kt++) {
        int cur = kt & 1;
        uint4 ra; uint4 rb[8];
        if (kt < 15) {
            int ko = (kt + 1) * 64;
            LOAD_A_CHUNK(ko, ra);
#pragma unroll
            for (int q = 0; q < 8; q++) rb[q] = *(const uint4*)(bsrc + q * 32768 + ko);
        }
        __syncthreads();
        if (kt < 15) {
            *(uint4*)&A_lds[cur ^ 1][aw] = ra;
#pragma unroll
            for (int q = 0; q < 8; q++) *(uint4*)&B_lds[cur ^ 1][(sm + q * 32) * 64 + bw] = rb[q];
        }
#pragma unroll
        for (int kw = 0; kw < 2; kw++) {
            int slot = ((kw * 4 + g) ^ axor) * 8;
            bf16x8 af[2], bf[4];
#pragma unroll
            for (int i = 0; i < 2; i++)
                af[i] = *(const bf16x8*)&A_lds[cur][((l & 15) + i * 16) * 64 + slot];
#pragma unroll
            for (int j = 0; j < 4; j++) {
                int c = w * 64 + j * 16 + (l & 15);
                bf[j] = *(const bf16x8*)&B_lds[cur][c * 64 + slot];
            }
#pragma unroll
            for (int i = 0; i < 2; i++)
#pragma unroll
                for (int j = 0; j < 4; j++)
                    acc[i][j] = __builtin_amdgcn_mfma_f32_16x16x32_bf16(af[i], bf[j], acc[i][j], 0, 0, 0);
        }
    }

    // epilogue: softmax over 256 cols per row, gate-scale, plain store to partial
    float* pbase = partial + (size_t)strm * (PART_ROWS * 256);
    float rmx[2][4], scale[2][4];

#pragma unroll
    for (int i = 0; i < 2; i++)
#pragma unroll
        for (int r = 0; r < 4; r++) {
            float mx = -1e30f;
#pragma unroll
            for (int j = 0; j < 4; j++) mx = fmaxf(mx, acc[i][j][r]);
#pragma unroll
            for (int s = 1; s < 16; s <<= 1) mx = fmaxf(mx, __shfl_xor(mx, s));
            if ((l & 15) == 0) s_red[i * 16 + g * 4 + r][w] = mx;
        }
    __syncthreads();
#pragma unroll
    for (int i = 0; i < 2; i++)
#pragma unroll
        for (int r = 0; r < 4; r++) {
            int row = i * 16 + g * 4 + r;
            rmx[i][r] = fmaxf(fmaxf(s_red[row][0], s_red[row][1]), fmaxf(s_red[row][2], s_red[row][3]));
        }
    __syncthreads();
#pragma unroll
    for (int i = 0; i < 2; i++)
#pragma unroll
        for (int r = 0; r < 4; r++) {
            float se = 0.f;
#pragma unroll
            for (int j = 0; j < 4; j++) {
                float v = __expf(acc[i][j][r] - rmx[i][r]);
                acc[i][j][r] = v;
                se += v;
            }
#pragma unroll
            for (int s = 1; s < 16; s <<= 1) se += __shfl_xor(se, s);
            if ((l & 15) == 0) s_red[i * 16 + g * 4 + r][w] = se;
        }
    __syncthreads();
#pragma unroll
    for (int i = 0; i < 2; i++)
#pragma unroll
        for (int r = 0; r < 4; r++) {
            int row = i * 16 + g * 4 + r;
            float tot = s_red[row][0] + s_red[row][1] + s_red[row][2] + s_red[row][3];
            scale[i][r] = gate_s[row] / tot;
        }
#pragma unroll
    for (int i = 0; i < 2; i++)
#pragma unroll
        for (int r = 0; r < 4; r++) {
            int row = i * 16 + g * 4 + r;
            int prow = pid_s[row];
            float sc = scale[i][r];
            float* pr = pbase + (size_t)prow * 256;
#pragma unroll
            for (int j = 0; j < 4; j++) {
                int col = w * 64 + j * 16 + (l & 15);
                pr[col] = acc[i][j][r] * sc;
            }
        }
#undef LOAD_A_CHUNK
}

// ---------------- pair-sum + log (fast path) ----------------
__global__ void log_pair_kernel(const float* __restrict__ partial, float* __restrict__ out, int n4)
{
    int i = blockIdx.x * 256 + threadIdx.x;
    if (i >= n4) return;
    int flat = i * 4;                   // element index in out (3*NB*CC)
    int strm = flat >> 20;              // / (NB*CC)
    int rem = flat & 1048575;
    int b = rem >> 8;
    int c = rem & 255;
    const float* p0 = partial + (size_t)strm * (PART_ROWS * 256) + (size_t)(2 * b) * 256 + c;
    float4 v0 = *(const float4*)p0;
    float4 v1 = *(const float4*)(p0 + 256);
    const float EPSL = 2.2204460492503131e-16f;
    float4 v;
    v.x = v0.x + v1.x; v.y = v0.y + v1.y; v.z = v0.z + v1.z; v.w = v0.w + v1.w;
    v.x = logf(v.x == 0.f ? EPSL : v.x);
    v.y = logf(v.y == 0.f ? EPSL : v.y);
    v.z = logf(v.z == 0.f ? EPSL : v.z);
    v.w = logf(v.w == 0.f ? EPSL : v.w);
    *(float4*)(out + (size_t)flat) = v;
}

// ---------------- fallback fp32 combine (atomic, known-good) ----------------
__global__ __launch_bounds__(256) void combine_kernel(
    const float* __restrict__ sf, const float* __restrict__ of,
    const float* __restrict__ ppf, const float* __restrict__ pvf,
    const float* __restrict__ Ws, const float* __restrict__ Wo, const float* __restrict__ Wp,
    const int* __restrict__ counts, const int* __restrict__ off, const int* __restrict__ toff,
    const int* __restrict__ rowlist, const float* __restrict__ gval,
    float* __restrict__ out)
{
    int bid = blockIdx.x;
    int strm = blockIdx.z;
    if (bid >= toff[8]) return;
    int e = 0;
    while (bid >= toff[e + 1]) e++;
    int tm = bid - toff[e];
    int cnt = counts[e];
    int obase = off[e];

    __shared__ float As[32][36];
    __shared__ float Bs[32][256];
    __shared__ int rows_s[32];
    __shared__ float gate_s[32];

    int t = threadIdx.x;
    if (t < 32) {
        int m = tm * 32 + t;
        if (m < cnt) {
            int pid = rowlist[obase + m];
            rows_s[t] = pid >> 1;
            gate_s[t] = gval[pid];
        } else {
            rows_s[t] = -1;
            gate_s[t] = 0.f;
        }
    }
    __syncthreads();

    const float* W = ((strm == 0) ? Ws : (strm == 1) ? Wo : Wp) + (size_t)e * DD * CC;
    float acc[2][16];
#pragma unroll
    for (int i = 0; i < 2; i++)
#pragma unroll
        for (int j = 0; j < 16; j++) acc[i][j] = 0.f;

    int tx = t & 15, ty = t >> 4;
    int r_st = t >> 3, d4 = t & 7;
    int row_st = rows_s[r_st];

    for (int k0 = 0; k0 < DD; k0 += 32) {
        float4 v = make_float4(0.f, 0.f, 0.f, 0.f);
        if (row_st >= 0) {
            int d = k0 + d4 * 4;
            if (strm == 0)      v = *(const float4*)(sf + (size_t)row_st * DD + d);
            else if (strm == 1) v = *(const float4*)(of + (size_t)row_st * DD + d);
            else v = (d < 512) ? *(const float4*)(ppf + (size_t)row_st * 512 + d)
                               : *(const float4*)(pvf + (size_t)row_st * 512 + (d - 512));
        }
        As[d4 * 4 + 0][r_st] = v.x;
        As[d4 * 4 + 1][r_st] = v.y;
        As[d4 * 4 + 2][r_st] = v.z;
        As[d4 * 4 + 3][r_st] = v.w;
#pragma unroll
        for (int j = 0; j < 8; j++) {
            int vv = t + 256 * j;
            int k = vv >> 6, c4 = vv & 63;
            *(float4*)&Bs[k][c4 * 4] = *(const float4*)&W[(size_t)(k0 + k) * CC + c4 * 4];
        }
        __syncthreads();

#pragma unroll
        for (int k = 0; k < 32; k++) {
            float2 a = *(float2*)&As[k][ty * 2];
#pragma unroll
            for (int jj = 0; jj < 4; jj++) {
                float4 bb = *(float4*)&Bs[k][jj * 64 + tx * 4];
                acc[0][jj * 4 + 0] += a.x * bb.x;
                acc[0][jj * 4 + 1] += a.x * bb.y;
                acc[0][jj * 4 + 2] += a.x * bb.z;
                acc[0][jj * 4 + 3] += a.x * bb.w;
                acc[1][jj * 4 + 0] += a.y * bb.x;
                acc[1][jj * 4 + 1] += a.y * bb.y;
                acc[1][jj * 4 + 2] += a.y * bb.z;
                acc[1][jj * 4 + 3] += a.y * bb.w;
            }
        }
        __syncthreads();
    }

    float* comb = out + (size_t)strm * (NB * CC);
#pragma unroll
    for (int i = 0; i < 2; i++) {
        int r = ty * 2 + i;
        int row = rows_s[r];
        if (row < 0) continue;
        float mx = -1e30f;
#pragma unroll
        for (int j = 0; j < 16; j++) mx = fmaxf(mx, acc[i][j]);
        for (int s = 1; s < 16; s <<= 1) mx = fmaxf(mx, __shfl_xor(mx, s, 16));
        float se = 0.f;
#pragma unroll
        for (int j = 0; j < 16; j++) { acc[i][j] = expf(acc[i][j] - mx); se += acc[i][j]; }
        for (int s = 1; s < 16; s <<= 1) se += __shfl_xor(se, s, 16);
        float scale = gate_s[r] / se;
#pragma unroll
        for (int jj = 0; jj < 4; jj++)
#pragma unroll
            for (int jo = 0; jo < 4; jo++) {
                int col = jj * 64 + tx * 4 + jo;
                atomicAdd(comb + (size_t)row * CC + col, acc[i][jj * 4 + jo] * scale);
            }
    }
}

__global__ void log_kernel(float* __restrict__ out, int n4)
{
    int i = blockIdx.x * 256 + threadIdx.x;
    if (i >= n4) return;
    float4 v = *(float4*)(out + (size_t)i * 4);
    const float EPSL = 2.2204460492503131e-16f;
    v.x = logf(v.x == 0.f ? EPSL : v.x);
    v.y = logf(v.y == 0.f ? EPSL : v.y);
    v.z = logf(v.z == 0.f ? EPSL : v.z);
    v.w = logf(v.w == 0.f ? EPSL : v.w);
    *(float4*)(out + (size_t)i * 4) = v;
}

extern "C" void kernel_launch(void* const* d_in, const int* in_sizes, int n_in,
                              void* d_out, int out_size, void* d_ws, size_t ws_size,
                              hipStream_t stream) {
    (void)in_sizes; (void)n_in;
    const float* sf    = (const float*)d_in[0];
    const float* of    = (const float*)d_in[1];
    const float* ppf   = (const float*)d_in[2];
    const float* pvf   = (const float*)d_in[3];
    const float* noise = (const float*)d_in[4];
    const float* wg    = (const float*)d_in[5];
    const float* wn    = (const float*)d_in[6];
    const float* Ws    = (const float*)d_in[7];
    const float* Wo    = (const float*)d_in[8];
    const float* Wp    = (const float*)d_in[9];
    float* out = (float*)d_out;

    char* ws = (char*)d_ws;
    int*   off     = (int*)(ws + 64);
    int*   toff    = (int*)(ws + 104);
    int*   counts  = (int*)(ws + 144);
    float* gval    = (float*)(ws + 256);
    int*   eidx    = (int*)(ws + 33024);
    int*   rowlist = (int*)(ws + 65792);
    float* cnt_p   = (float*)(ws + 98560);
    float* imp_p   = (float*)(ws + 131328);
    float* load_p  = (float*)(ws + 164096);
    unsigned short* Wt = (unsigned short*)(ws + WT_OFF);
    float* partial = (float*)(ws + PART_OFF);

    bool fast = ws_size >= WS_FAST_NEED;

    if (fast) {
        prep_w_kernel<<<1536, 256, 0, stream>>>(Ws, Wo, Wp, Wt);
    } else {
        hipMemsetAsync(d_out, 0, (size_t)out_size * sizeof(float), stream);
    }

    gating_kernel<<<NGBLK, 256, 0, stream>>>(sf, noise, wg, wn, gval, eidx, cnt_p, imp_p, load_p);
    scan_loss_kernel<<<1, 64, 0, stream>>>(cnt_p, imp_p, load_p, counts, off, toff, out + (out_size - 1));
    fill_kernel<<<1, 256, 0, stream>>>(eidx, off, rowlist);

    int n4 = (out_size - 1) / 4;
    if (fast) {
        combine_mfma_kernel<<<dim3(264, 1, 3), 256, 0, stream>>>(
            sf, of, ppf, pvf, Wt, counts, off, toff, rowlist, gval, partial);
        log_pair_kernel<<<(n4 + 255) / 256, 256, 0, stream>>>(partial, out, n4);
    } else {
        combine_kernel<<<dim3(2 * NB / 32 + 8, 1, 3), 256, 0, stream>>>(
            sf, of, ppf, pvf, Ws, Wo, Wp, counts, off, toff, rowlist, gval, out);
        log_kernel<<<(n4 + 255) / 256, 256, 0, stream>>>(out, n4);
    }
}

// Round 6
// 260.858 us; speedup vs baseline: 3.2315x; 1.2719x over previous
//
#include <hip/hip_runtime.h>
#include <math.h>

#define NB 4096
#define DD 1024
#define CC 256
#define NE 8
#define NGBLK 1024

typedef short bf16x8 __attribute__((ext_vector_type(8)));
typedef float f32x4 __attribute__((ext_vector_type(4)));

// ws layout (bytes):
//   64: off[9] | 104: toff32[9] | 144: counts[8] | 184: toff64[9]
//   256:    gval f32[8192] | 33024: eidx int[8192] | 65792: rowlist int[8192]
//   98560:  cnt_p f32[NGBLK*8] | 131328: imp_p | 164096: load_p
//   256KB:  Wt bf16 [24][256][1024]          (12.58 MB)   -- fast path
//   13MB:   partial f32 [3][8224][256]       (25.26 MB)   -- fast path
#define WT_OFF   262144ull
#define PART_OFF 13631488ull
#define PART_ROWS 8224
#define WS_FAST_NEED (41943040ull)

__device__ __forceinline__ unsigned short f2bf(float f) {
    union { float f; unsigned u; } v; v.f = f;
    unsigned x = v.u;
    return (unsigned short)((x + 0x7FFFu + ((x >> 16) & 1u)) >> 16);
}

// ---------------- gating ----------------
__global__ __launch_bounds__(256) void gating_kernel(
    const float* __restrict__ sf, const float* __restrict__ noise,
    const float* __restrict__ wg, const float* __restrict__ wn,
    float* __restrict__ gval, int* __restrict__ eidx,
    float* __restrict__ cnt_p, float* __restrict__ imp_p, float* __restrict__ load_p)
{
    int t = threadIdx.x;
    int lane = t & 63;
    int w = t >> 6;
    int b = blockIdx.x * 4 + w;
    const float* x = sf + (size_t)b * DD;

    float accg[8], accn[8];
#pragma unroll
    for (int e = 0; e < 8; e++) { accg[e] = 0.f; accn[e] = 0.f; }

#pragma unroll
    for (int q = 0; q < 16; q++) {
        int d = q * 64 + lane;
        float xs = x[d];
        float4 g0 = *(const float4*)(wg + (size_t)d * 8);
        float4 g1 = *(const float4*)(wg + (size_t)d * 8 + 4);
        float4 n0 = *(const float4*)(wn + (size_t)d * 8);
        float4 n1 = *(const float4*)(wn + (size_t)d * 8 + 4);
        accg[0] += xs * g0.x; accg[1] += xs * g0.y; accg[2] += xs * g0.z; accg[3] += xs * g0.w;
        accg[4] += xs * g1.x; accg[5] += xs * g1.y; accg[6] += xs * g1.z; accg[7] += xs * g1.w;
        accn[0] += xs * n0.x; accn[1] += xs * n0.y; accn[2] += xs * n0.z; accn[3] += xs * n0.w;
        accn[4] += xs * n1.x; accn[5] += xs * n1.y; accn[6] += xs * n1.z; accn[7] += xs * n1.w;
    }
#pragma unroll
    for (int e = 0; e < 8; e++) {
        for (int s = 1; s < 64; s <<= 1) {
            accg[e] += __shfl_xor(accg[e], s);
            accn[e] += __shfl_xor(accn[e], s);
        }
    }

    __shared__ float s_load[4][8], s_imp[4][8], s_cnt[4][8];

    if (lane == 0) {
        float clean[8], stdv[8], noisy[8], p[8];
        float mx = -1e30f;
#pragma unroll
        for (int e = 0; e < 8; e++) {
            clean[e] = accg[e];
            float xn = accn[e];
            float sp = (xn > 0.f) ? (xn + log1pf(expf(-xn))) : log1pf(expf(xn));
            stdv[e] = sp + 0.01f;
            noisy[e] = clean[e] + noise[(size_t)b * 8 + e] * stdv[e];
            mx = fmaxf(mx, noisy[e]);
        }
        float se = 0.f;
#pragma unroll
        for (int e = 0; e < 8; e++) { p[e] = expf(noisy[e] - mx); se += p[e]; }
        float inv = 1.f / se;
#pragma unroll
        for (int e = 0; e < 8; e++) p[e] *= inv;

        int i0 = -1, i1 = -1;
        float p0 = -1e30f, p1v = -1e30f, p2v = -1e30f;
#pragma unroll
        for (int e = 0; e < 8; e++) if (p[e] > p0) { p0 = p[e]; i0 = e; }
#pragma unroll
        for (int e = 0; e < 8; e++) if (e != i0 && p[e] > p1v) { p1v = p[e]; i1 = e; }
#pragma unroll
        for (int e = 0; e < 8; e++) if (e != i0 && e != i1 && p[e] > p2v) { p2v = p[e]; }

        float den = p0 + p1v + 1e-6f;
        float g0 = p0 / den, g1 = p1v / den;
        eidx[2 * b] = i0; eidx[2 * b + 1] = i1;
        gval[2 * b] = g0; gval[2 * b + 1] = g1;

        const float is2 = 0.70710678118654752440f;
#pragma unroll
        for (int e = 0; e < 8; e++) {
            float pin  = 0.5f * (1.f + erff((clean[e] - p2v) / stdv[e] * is2));
            float pout = 0.5f * (1.f + erff((clean[e] - p1v) / stdv[e] * is2));
            s_load[w][e] = (noisy[e] > p2v) ? pin : pout;
            s_imp[w][e]  = (e == i0) ? g0 : (e == i1) ? g1 : 0.f;
            s_cnt[w][e]  = (e == i0 || e == i1) ? 1.f : 0.f;
        }
    }
    __syncthreads();
    if (t < 8) {
        float sl = 0.f, si = 0.f, sc = 0.f;
#pragma unroll
        for (int ww = 0; ww < 4; ww++) {
            sl += s_load[ww][t]; si += s_imp[ww][t]; sc += s_cnt[ww][t];
        }
        load_p[blockIdx.x * 8 + t] = sl;
        imp_p [blockIdx.x * 8 + t] = si;
        cnt_p [blockIdx.x * 8 + t] = sc;
    }
}

__global__ void scan_loss_kernel(const float* __restrict__ cnt_p, const float* __restrict__ imp_p,
                                 const float* __restrict__ load_p,
                                 int* __restrict__ counts, int* __restrict__ off,
                                 int* __restrict__ toff32, int* __restrict__ toff64,
                                 float* __restrict__ out_loss)
{
    __shared__ float s_c[64], s_i[64], s_l[64];
    __shared__ float f_c[8], f_i[8], f_l[8];
    int t = threadIdx.x;
    int e = t & 7, g = t >> 3;
    float sc = 0.f, si = 0.f, sl = 0.f;
    for (int blk = g * 128; blk < (g + 1) * 128; blk++) {
        sc += cnt_p[blk * 8 + e];
        si += imp_p[blk * 8 + e];
        sl += load_p[blk * 8 + e];
    }
    s_c[t] = sc; s_i[t] = si; s_l[t] = sl;
    __syncthreads();
    if (t < 8) {
        float c = 0.f, i = 0.f, l = 0.f;
        for (int gg = 0; gg < 8; gg++) { c += s_c[gg * 8 + t]; i += s_i[gg * 8 + t]; l += s_l[gg * 8 + t]; }
        f_c[t] = c; f_i[t] = i; f_l[t] = l;
        counts[t] = (int)(c + 0.5f);
    }
    __syncthreads();
    if (t == 0) {
        int o = 0, t32 = 0, t64 = 0;
        off[0] = 0; toff32[0] = 0; toff64[0] = 0;
        for (int ee = 0; ee < 8; ee++) {
            int c = (int)(f_c[ee] + 0.5f);
            o += c; off[ee + 1] = o;
            t32 += (c + 31) / 32; toff32[ee + 1] = t32;
            t64 += (c + 63) / 64; toff64[ee + 1] = t64;
        }
        float mi = 0.f, ml = 0.f;
        for (int ee = 0; ee < 8; ee++) { mi += f_i[ee]; ml += f_l[ee]; }
        mi *= 0.125f; ml *= 0.125f;
        float vi = 0.f, vl = 0.f;
        for (int ee = 0; ee < 8; ee++) {
            float di = f_i[ee] - mi; vi += di * di;
            float dl = f_l[ee] - ml; vl += dl * dl;
        }
        vi /= 7.f; vl /= 7.f;
        out_loss[0] = (vi / (mi * mi + 1e-10f) + vl / (ml * ml + 1e-10f)) * 0.01f;
    }
}

// ---------------- deterministic fill: counting sort, single block ----------------
__global__ __launch_bounds__(256) void fill_kernel(
    const int* __restrict__ eidx, const int* __restrict__ off, int* __restrict__ rowlist)
{
    __shared__ int hist[256][8];
    __shared__ int off_s[8];
    int t = threadIdx.x;
    if (t < 8) off_s[t] = off[t];
    int base = t * 32;
    int le[32];
    int c[8];
#pragma unroll
    for (int e = 0; e < 8; e++) c[e] = 0;
#pragma unroll
    for (int j = 0; j < 32; j++) {
        int ev = eidx[base + j];
        le[j] = ev;
#pragma unroll
        for (int e = 0; e < 8; e++) c[e] += (ev == e) ? 1 : 0;
    }
#pragma unroll
    for (int e = 0; e < 8; e++) hist[t][e] = c[e];
    __syncthreads();
    if (t < 8) {
        int run = 0;
        for (int i = 0; i < 256; i++) { int v = hist[i][t]; hist[i][t] = run; run += v; }
    }
    __syncthreads();
#pragma unroll
    for (int j = 0; j < 32; j++) {
        int ev = le[j];
        int p = hist[t][ev];
        hist[t][ev] = p + 1;
        rowlist[off_s[ev] + p] = base + j;
    }
}

// ---------------- prep: W [e][k][c] -> Wt [e'][c][k] bf16 ----------------
__global__ __launch_bounds__(256) void prep_w_kernel(
    const float* __restrict__ Ws, const float* __restrict__ Wo, const float* __restrict__ Wp,
    unsigned short* __restrict__ Wt)
{
    __shared__ unsigned short LT[64][68];
    int bid = blockIdx.x;
    int ep = bid >> 6;
    int rem = bid & 63;
    int k0 = (rem >> 2) * 64;
    int c0 = (rem & 3) * 64;
    int strm = ep >> 3, e = ep & 7;
    const float* W = ((strm == 0) ? Ws : (strm == 1) ? Wo : Wp) + (size_t)e * (1024 * 256);

    int t = threadIdx.x;
    int c_l = t & 63;
    int kb = t >> 6;
#pragma unroll
    for (int r = 0; r < 16; r++) {
        int k_l = r * 4 + kb;
        LT[c_l][k_l] = f2bf(W[(size_t)(k0 + k_l) * 256 + c0 + c_l]);
    }
    __syncthreads();

    int cw = t >> 2, kq = t & 3;
    unsigned short* dst_row = Wt + (size_t)ep * 262144 + (size_t)(c0 + cw) * 1024 + k0;
#pragma unroll
    for (int p = 0; p < 2; p++) {
        int kqp = kq + p * 4;
        ushort4 a = *(ushort4*)&LT[cw][kqp * 8];
        ushort4 b = *(ushort4*)&LT[cw][kqp * 8 + 4];
        uint4 o;
        o.x = (unsigned)a.x | ((unsigned)a.y << 16);
        o.y = (unsigned)a.z | ((unsigned)a.w << 16);
        o.z = (unsigned)b.x | ((unsigned)b.y << 16);
        o.w = (unsigned)b.z | ((unsigned)b.w << 16);
        *(uint4*)(dst_row + kqp * 8) = o;
    }
}

// ---------------- MFMA combine: BM=64, BN=256, BK=64, 8 waves, 1-barrier pipeline ----------------
__global__ __launch_bounds__(512) void combine_mfma_kernel(
    const float* __restrict__ sf, const float* __restrict__ of,
    const float* __restrict__ ppf, const float* __restrict__ pvf,
    const unsigned short* __restrict__ Wt,
    const int* __restrict__ counts, const int* __restrict__ off, const int* __restrict__ toff64,
    const int* __restrict__ rowlist, const float* __restrict__ gval,
    float* __restrict__ partial)
{
    int bid = blockIdx.x;
    int strm = blockIdx.z;
    if (bid >= toff64[8]) return;
    int e = 0;
    while (bid >= toff64[e + 1]) e++;
    int tm = bid - toff64[e];
    int cnt = counts[e];
    int obase = off[e];
    int ep = strm * 8 + e;

    __shared__ unsigned short A_lds[2][64 * 64];    // 16 KB
    __shared__ unsigned short B_lds[2][256 * 64];   // 64 KB  -> total exactly 80 KiB, 2 blocks/CU

    int t = threadIdx.x;
    int l = t & 63, w = t >> 6;         // 8 waves
    int wr = w >> 2, wc = w & 3;        // 2 x 4 wave grid

    // staging roles: thread covers A row sm (16B chunk ss) and B rows sm+q*64
    int sm = t >> 3;                    // 0..63
    int ss = t & 7;                     // 0..7
    int m_st = tm * 64 + sm;
    int pid_st = (m_st < cnt) ? rowlist[obase + m_st] : 8192;
    int arow = (pid_st >= 8192) ? 0 : (pid_st >> 1);
    const float* a01 = (strm == 0) ? (sf + (size_t)arow * DD) : (of + (size_t)arow * DD);
    const float* app = ppf + (size_t)arow * 512;
    const float* apv = pvf + (size_t)arow * 512;
    const unsigned short* bsrc = Wt + (size_t)ep * 262144 + (size_t)sm * 1024 + ss * 8;
    int aw = sm * 64 + ((ss ^ (sm & 7)) * 8);
    int bw = (ss ^ (sm & 7)) * 8;

#define LOAD_A(ko, dst)                                                    \
    {                                                                      \
        int kk = (ko) + ss * 8;                                            \
        const float* s_;                                                   \
        if (strm != 2) s_ = a01 + kk;                                      \
        else s_ = (kk < 512) ? (app + kk) : (apv + (kk - 512));            \
        float4 f0 = *(const float4*)s_;                                    \
        float4 f1 = *(const float4*)(s_ + 4);                              \
        dst.x = (unsigned)f2bf(f0.x) | ((unsigned)f2bf(f0.y) << 16);       \
        dst.y = (unsigned)f2bf(f0.z) | ((unsigned)f2bf(f0.w) << 16);       \
        dst.z = (unsigned)f2bf(f1.x) | ((unsigned)f2bf(f1.y) << 16);       \
        dst.w = (unsigned)f2bf(f1.z) | ((unsigned)f2bf(f1.w) << 16);       \
    }

    // prologue: stage tile 0 into buf 0
    {
        uint4 ra; LOAD_A(0, ra);
        uint4 rb[4];
#pragma unroll
        for (int q = 0; q < 4; q++) rb[q] = *(const uint4*)(bsrc + q * 65536);
        *(uint4*)&A_lds[0][aw] = ra;
#pragma unroll
        for (int q = 0; q < 4; q++) *(uint4*)&B_lds[0][(sm + q * 64) * 64 + bw] = rb[q];
    }

    f32x4 acc[2][4];
#pragma unroll
    for (int i = 0; i < 2; i++)
#pragma unroll
        for (int j = 0; j < 4; j++)
#pragma unroll
            for (int r = 0; r < 4; r++) acc[i][j][r] = 0.f;

    int g = l >> 4;
    int axor = l & 7;

    for (int kt = 0; kt < 16; kt++) {
        int cur = kt & 1;
        uint4 ra; uint4 rb[4];
        if (kt < 15) {
            int ko = (kt + 1) * 64;
            LOAD_A(ko, ra);
#pragma unroll
            for (int q = 0; q < 4; q++) rb[q] = *(const uint4*)(bsrc + q * 65536 + ko);
        }
        __syncthreads();   // buf[cur] writes visible; everyone done reading buf[cur^1]
        // MFMA on buf[cur] while the next tile's loads are in flight
#pragma unroll
        for (int kw = 0; kw < 2; kw++) {
            int slot = ((kw * 4 + g) ^ axor) * 8;
            bf16x8 af[2], bf[4];
#pragma unroll
            for (int i = 0; i < 2; i++)
                af[i] = *(const bf16x8*)&A_lds[cur][(wr * 32 + (l & 15) + i * 16) * 64 + slot];
#pragma unroll
            for (int j = 0; j < 4; j++)
                bf[j] = *(const bf16x8*)&B_lds[cur][(wc * 64 + j * 16 + (l & 15)) * 64 + slot];
#pragma unroll
            for (int i = 0; i < 2; i++)
#pragma unroll
                for (int j = 0; j < 4; j++)
                    acc[i][j] = __builtin_amdgcn_mfma_f32_16x16x32_bf16(af[i], bf[j], acc[i][j], 0, 0, 0);
        }
        if (kt < 15) {
            *(uint4*)&A_lds[cur ^ 1][aw] = ra;
#pragma unroll
            for (int q = 0; q < 4; q++) *(uint4*)&B_lds[cur ^ 1][(sm + q * 64) * 64 + bw] = rb[q];
        }
    }
#undef LOAD_A

    __syncthreads();                       // A_lds dead -> reuse for reductions
    float* s_red = (float*)&A_lds[0][0];   // [64][4]

    // per-thread row metadata (8 rows: wr,g fixed; i in {0,1}, r in {0..3})
    float gate_r[2][4];
    int pid_r[2][4];
#pragma unroll
    for (int i = 0; i < 2; i++)
#pragma unroll
        for (int r = 0; r < 4; r++) {
            int row = wr * 32 + i * 16 + g * 4 + r;
            int m = tm * 64 + row;
            int pid = (m < cnt) ? rowlist[obase + m] : 8192;
            pid_r[i][r] = pid;
            gate_r[i][r] = (m < cnt) ? gval[pid] : 0.f;
        }

    float rmx[2][4], scale[2][4];
#pragma unroll
    for (int i = 0; i < 2; i++)
#pragma unroll
        for (int r = 0; r < 4; r++) {
            float mx = -1e30f;
#pragma unroll
            for (int j = 0; j < 4; j++) mx = fmaxf(mx, acc[i][j][r]);
#pragma unroll
            for (int s = 1; s < 16; s <<= 1) mx = fmaxf(mx, __shfl_xor(mx, s));
            if ((l & 15) == 0) s_red[(wr * 32 + i * 16 + g * 4 + r) * 4 + wc] = mx;
        }
    __syncthreads();
#pragma unroll
    for (int i = 0; i < 2; i++)
#pragma unroll
        for (int r = 0; r < 4; r++) {
            int row = wr * 32 + i * 16 + g * 4 + r;
            rmx[i][r] = fmaxf(fmaxf(s_red[row * 4 + 0], s_red[row * 4 + 1]),
                              fmaxf(s_red[row * 4 + 2], s_red[row * 4 + 3]));
        }
    __syncthreads();
#pragma unroll
    for (int i = 0; i < 2; i++)
#pragma unroll
        for (int r = 0; r < 4; r++) {
            float se = 0.f;
#pragma unroll
            for (int j = 0; j < 4; j++) {
                float v = __expf(acc[i][j][r] - rmx[i][r]);
                acc[i][j][r] = v;
                se += v;
            }
#pragma unroll
            for (int s = 1; s < 16; s <<= 1) se += __shfl_xor(se, s);
            if ((l & 15) == 0) s_red[(wr * 32 + i * 16 + g * 4 + r) * 4 + wc] = se;
        }
    __syncthreads();
#pragma unroll
    for (int i = 0; i < 2; i++)
#pragma unroll
        for (int r = 0; r < 4; r++) {
            int row = wr * 32 + i * 16 + g * 4 + r;
            float tot = s_red[row * 4 + 0] + s_red[row * 4 + 1] + s_red[row * 4 + 2] + s_red[row * 4 + 3];
            scale[i][r] = gate_r[i][r] / tot;
        }

    float* pbase = partial + (size_t)strm * (PART_ROWS * 256);
#pragma unroll
    for (int i = 0; i < 2; i++)
#pragma unroll
        for (int r = 0; r < 4; r++) {
            float* pr = pbase + (size_t)pid_r[i][r] * 256;
            float sc = scale[i][r];
#pragma unroll
            for (int j = 0; j < 4; j++) {
                int col = wc * 64 + j * 16 + (l & 15);
                pr[col] = acc[i][j][r] * sc;
            }
        }
}

// ---------------- pair-sum + log (fast path) ----------------
__global__ void log_pair_kernel(const float* __restrict__ partial, float* __restrict__ out, int n4)
{
    int i = blockIdx.x * 256 + threadIdx.x;
    if (i >= n4) return;
    int flat = i * 4;
    int strm = flat >> 20;
    int rem = flat & 1048575;
    int b = rem >> 8;
    int c = rem & 255;
    const float* p0 = partial + (size_t)strm * (PART_ROWS * 256) + (size_t)(2 * b) * 256 + c;
    float4 v0 = *(const float4*)p0;
    float4 v1 = *(const float4*)(p0 + 256);
    const float EPSL = 2.2204460492503131e-16f;
    float4 v;
    v.x = v0.x + v1.x; v.y = v0.y + v1.y; v.z = v0.z + v1.z; v.w = v0.w + v1.w;
    v.x = logf(v.x == 0.f ? EPSL : v.x);
    v.y = logf(v.y == 0.f ? EPSL : v.y);
    v.z = logf(v.z == 0.f ? EPSL : v.z);
    v.w = logf(v.w == 0.f ? EPSL : v.w);
    *(float4*)(out + (size_t)flat) = v;
}

// ---------------- fallback fp32 combine (atomic, known-good) ----------------
__global__ __launch_bounds__(256) void combine_kernel(
    const float* __restrict__ sf, const float* __restrict__ of,
    const float* __restrict__ ppf, const float* __restrict__ pvf,
    const float* __restrict__ Ws, const float* __restrict__ Wo, const float* __restrict__ Wp,
    const int* __restrict__ counts, const int* __restrict__ off, const int* __restrict__ toff,
    const int* __restrict__ rowlist, const float* __restrict__ gval,
    float* __restrict__ out)
{
    int bid = blockIdx.x;
    int strm = blockIdx.z;
    if (bid >= toff[8]) return;
    int e = 0;
    while (bid >= toff[e + 1]) e++;
    int tm = bid - toff[e];
    int cnt = counts[e];
    int obase = off[e];

    __shared__ float As[32][36];
    __shared__ float Bs[32][256];
    __shared__ int rows_s[32];
    __shared__ float gate_s[32];

    int t = threadIdx.x;
    if (t < 32) {
        int m = tm * 32 + t;
        if (m < cnt) {
            int pid = rowlist[obase + m];
            rows_s[t] = pid >> 1;
            gate_s[t] = gval[pid];
        } else {
            rows_s[t] = -1;
            gate_s[t] = 0.f;
        }
    }
    __syncthreads();

    const float* W = ((strm == 0) ? Ws : (strm == 1) ? Wo : Wp) + (size_t)e * DD * CC;
    float acc[2][16];
#pragma unroll
    for (int i = 0; i < 2; i++)
#pragma unroll
        for (int j = 0; j < 16; j++) acc[i][j] = 0.f;

    int tx = t & 15, ty = t >> 4;
    int r_st = t >> 3, d4 = t & 7;
    int row_st = rows_s[r_st];

    for (int k0 = 0; k0 < DD; k0 += 32) {
        float4 v = make_float4(0.f, 0.f, 0.f, 0.f);
        if (row_st >= 0) {
            int d = k0 + d4 * 4;
            if (strm == 0)      v = *(const float4*)(sf + (size_t)row_st * DD + d);
            else if (strm == 1) v = *(const float4*)(of + (size_t)row_st * DD + d);
            else v = (d < 512) ? *(const float4*)(ppf + (size_t)row_st * 512 + d)
                               : *(const float4*)(pvf + (size_t)row_st * 512 + (d - 512));
        }
        As[d4 * 4 + 0][r_st] = v.x;
        As[d4 * 4 + 1][r_st] = v.y;
        As[d4 * 4 + 2][r_st] = v.z;
        As[d4 * 4 + 3][r_st] = v.w;
#pragma unroll
        for (int j = 0; j < 8; j++) {
            int vv = t + 256 * j;
            int k = vv >> 6, c4 = vv & 63;
            *(float4*)&Bs[k][c4 * 4] = *(const float4*)&W[(size_t)(k0 + k) * CC + c4 * 4];
        }
        __syncthreads();

#pragma unroll
        for (int k = 0; k < 32; k++) {
            float2 a = *(float2*)&As[k][ty * 2];
#pragma unroll
            for (int jj = 0; jj < 4; jj++) {
                float4 bb = *(float4*)&Bs[k][jj * 64 + tx * 4];
                acc[0][jj * 4 + 0] += a.x * bb.x;
                acc[0][jj * 4 + 1] += a.x * bb.y;
                acc[0][jj * 4 + 2] += a.x * bb.z;
                acc[0][jj * 4 + 3] += a.x * bb.w;
                acc[1][jj * 4 + 0] += a.y * bb.x;
                acc[1][jj * 4 + 1] += a.y * bb.y;
                acc[1][jj * 4 + 2] += a.y * bb.z;
                acc[1][jj * 4 + 3] += a.y * bb.w;
            }
        }
        __syncthreads();
    }

    float* comb = out + (size_t)strm * (NB * CC);
#pragma unroll
    for (int i = 0; i < 2; i++) {
        int r = ty * 2 + i;
        int row = rows_s[r];
        if (row < 0) continue;
        float mx = -1e30f;
#pragma unroll
        for (int j = 0; j < 16; j++) mx = fmaxf(mx, acc[i][j]);
        for (int s = 1; s < 16; s <<= 1) mx = fmaxf(mx, __shfl_xor(mx, s, 16));
        float se = 0.f;
#pragma unroll
        for (int j = 0; j < 16; j++) { acc[i][j] = expf(acc[i][j] - mx); se += acc[i][j]; }
        for (int s = 1; s < 16; s <<= 1) se += __shfl_xor(se, s, 16);
        float scale = gate_s[r] / se;
#pragma unroll
        for (int jj = 0; jj < 4; jj++)
#pragma unroll
            for (int jo = 0; jo < 4; jo++) {
                int col = jj * 64 + tx * 4 + jo;
                atomicAdd(comb + (size_t)row * CC + col, acc[i][jj * 4 + jo] * scale);
            }
    }
}

__global__ void log_kernel(float* __restrict__ out, int n4)
{
    int i = blockIdx.x * 256 + threadIdx.x;
    if (i >= n4) return;
    float4 v = *(float4*)(out + (size_t)i * 4);
    const float EPSL = 2.2204460492503131e-16f;
    v.x = logf(v.x == 0.f ? EPSL : v.x);
    v.y = logf(v.y == 0.f ? EPSL : v.y);
    v.z = logf(v.z == 0.f ? EPSL : v.z);
    v.w = logf(v.w == 0.f ? EPSL : v.w);
    *(float4*)(out + (size_t)i * 4) = v;
}

extern "C" void kernel_launch(void* const* d_in, const int* in_sizes, int n_in,
                              void* d_out, int out_size, void* d_ws, size_t ws_size,
                              hipStream_t stream) {
    (void)in_sizes; (void)n_in;
    const float* sf    = (const float*)d_in[0];
    const float* of    = (const float*)d_in[1];
    const float* ppf   = (const float*)d_in[2];
    const float* pvf   = (const float*)d_in[3];
    const float* noise = (const float*)d_in[4];
    const float* wg    = (const float*)d_in[5];
    const float* wn    = (const float*)d_in[6];
    const float* Ws    = (const float*)d_in[7];
    const float* Wo    = (const float*)d_in[8];
    const float* Wp    = (const float*)d_in[9];
    float* out = (float*)d_out;

    char* ws = (char*)d_ws;
    int*   off     = (int*)(ws + 64);
    int*   toff32  = (int*)(ws + 104);
    int*   counts  = (int*)(ws + 144);
    int*   toff64  = (int*)(ws + 184);
    float* gval    = (float*)(ws + 256);
    int*   eidx    = (int*)(ws + 33024);
    int*   rowlist = (int*)(ws + 65792);
    float* cnt_p   = (float*)(ws + 98560);
    float* imp_p   = (float*)(ws + 131328);
    float* load_p  = (float*)(ws + 164096);
    unsigned short* Wt = (unsigned short*)(ws + WT_OFF);
    float* partial = (float*)(ws + PART_OFF);

    bool fast = ws_size >= WS_FAST_NEED;

    if (fast) {
        prep_w_kernel<<<1536, 256, 0, stream>>>(Ws, Wo, Wp, Wt);
    } else {
        hipMemsetAsync(d_out, 0, (size_t)out_size * sizeof(float), stream);
    }

    gating_kernel<<<NGBLK, 256, 0, stream>>>(sf, noise, wg, wn, gval, eidx, cnt_p, imp_p, load_p);
    scan_loss_kernel<<<1, 64, 0, stream>>>(cnt_p, imp_p, load_p, counts, off, toff32, toff64, out + (out_size - 1));
    fill_kernel<<<1, 256, 0, stream>>>(eidx, off, rowlist);

    int n4 = (out_size - 1) / 4;
    if (fast) {
        combine_mfma_kernel<<<dim3(136, 1, 3), 512, 0, stream>>>(
            sf, of, ppf, pvf, Wt, counts, off, toff64, rowlist, gval, partial);
        log_pair_kernel<<<(n4 + 255) / 256, 256, 0, stream>>>(partial, out, n4);
    } else {
        combine_kernel<<<dim3(2 * NB / 32 + 8, 1, 3), 256, 0, stream>>>(
            sf, of, ppf, pvf, Ws, Wo, Wp, counts, off, toff32, rowlist, gval, out);
        log_kernel<<<(n4 + 255) / 256, 256, 0, stream>>>(out, n4);
    }
}